// Round 8
// baseline (2499.514 us; speedup 1.0000x reference)
//
#include <hip/hip_runtime.h>
#include <hip/hip_cooperative_groups.h>

// ---------------------------------------------------------------------------
// TransMIL forward on MI355X.
//   r0: 12995 us baseline (all-fp32, classic 64x64 tiled GEMMs).
//   r1: 10182 us — PPEG collapsed to one combined 7x7 depthwise conv.
//   r2:  8278 us — out_kernel rewritten as fused 32-token tile kernel.
//   r3:  5546 us — a3v rewritten as split-K flash attention.
//   r4:  3723 us — fc1/qkv/proj GEMMs -> bf16 MFMA (16x16x32).
//   r5:  3025 us — a3v_part -> bf16 MFMA flash.
//   r6:  1735 us — out_tile -> bf16 MFMA; bmm256 -> split-bf16 MFMA.
//   r7: pinv chain (27 dispatches/layer) -> ONE cooperative kernel with
//       grid.sync() between the 24 bmm stages; GEMM tile core BK 32->64
//       (half the barriers per MFMA).
// ---------------------------------------------------------------------------

namespace cg = cooperative_groups;

constexpr int D_    = 512;
constexpr int E_    = 1024;
constexpr int NTOK  = 20737;
constexpr int NP_   = 20992;   // padded seq len (255 zero rows at FRONT)
constexpr int NH_   = 8;
constexpr int HD_   = 64;
constexpr int MLM   = 256;     // landmarks
constexpr int LCH   = 82;      // tokens per landmark
constexpr int HHW   = 144;
constexpr int NFEAT = 20736;   // 144*144
constexpr int PADR  = 255;
constexpr int NCH   = 41;      // a3v N-chunks
constexpr int CHTOK = 512;     // tokens per chunk (8 subchunks of 64)

typedef __attribute__((ext_vector_type(8))) short bf16x8;
typedef __attribute__((ext_vector_type(4))) float f32x4;

__device__ __forceinline__ unsigned short f2bf(float f){
  unsigned int u = __float_as_uint(f);
  unsigned int r = u + 0x7fffu + ((u >> 16) & 1u);
  return (unsigned short)(r >> 16);
}
__device__ __forceinline__ float bfu(unsigned short u){
  return __uint_as_float((unsigned int)u << 16);
}

// ---------------- reduction helpers ----------------
__device__ __forceinline__ float waveMaxF(float v){
#pragma unroll
  for (int o = 32; o > 0; o >>= 1) v = fmaxf(v, __shfl_xor(v, o));
  return v;
}
__device__ __forceinline__ float waveSumF(float v){
#pragma unroll
  for (int o = 32; o > 0; o >>= 1) v += __shfl_xor(v, o);
  return v;
}
__device__ __forceinline__ float blockMax256(float v, float* sbuf){
  v = waveMaxF(v);
  if ((threadIdx.x & 63) == 0) sbuf[threadIdx.x >> 6] = v;
  __syncthreads();
  float r = fmaxf(fmaxf(sbuf[0], sbuf[1]), fmaxf(sbuf[2], sbuf[3]));
  __syncthreads();
  return r;
}
__device__ __forceinline__ float blockSum256(float v, float* sbuf){
  v = waveSumF(v);
  if ((threadIdx.x & 63) == 0) sbuf[threadIdx.x >> 6] = v;
  __syncthreads();
  float r = sbuf[0] + sbuf[1] + sbuf[2] + sbuf[3];
  __syncthreads();
  return r;
}

// ---------------- weight prep: W[K][N] fp32 -> Wt[N][K] bf16 ----------------
__global__ __launch_bounds__(256) void wtrans_kernel(
    const float* __restrict__ W, unsigned short* __restrict__ Wt, int K, int N){
  __shared__ float tile[32][33];
  const int kb = blockIdx.x * 32, nb = blockIdx.y * 32;
  const int tx = threadIdx.x, ty = threadIdx.y;
  for (int i = ty; i < 32; i += 8) tile[i][tx] = W[(size_t)(kb + i) * N + nb + tx];
  __syncthreads();
  for (int i = ty; i < 32; i += 8)
    Wt[(size_t)(nb + i) * K + kb + tx] = f2bf(tile[tx][i]);
}

// ---------------- maxpool2 + bf16 ----------------
__global__ __launch_bounds__(256) void pool_bf16_kernel(
    const float* __restrict__ x, unsigned short* __restrict__ Ah){
  size_t idx4 = ((size_t)blockIdx.x * 256 + threadIdx.x) * 4;
  size_t m = idx4 >> 10, e = idx4 & 1023;
  float4 a = *(const float4*)(x + (m * 2) * E_ + e);
  float4 b = *(const float4*)(x + (m * 2 + 1) * E_ + e);
  unsigned long long pk =
      (unsigned long long)f2bf(fmaxf(a.x, b.x))
    | ((unsigned long long)f2bf(fmaxf(a.y, b.y)) << 16)
    | ((unsigned long long)f2bf(fmaxf(a.z, b.z)) << 32)
    | ((unsigned long long)f2bf(fmaxf(a.w, b.w)) << 48);
  *(unsigned long long*)(Ah + idx4) = pk;
}

// ---------------- MFMA 64x64 tile core, BK=64 (bf16 in, fp32 acc) ----------
// As/Bs: 64 rows x 72 shorts (64 data + 8 pad). 8 MFMAs per barrier pair.
__device__ __forceinline__ void mfma_tile64(
    const unsigned short* __restrict__ A, int arows, int bm,
    const unsigned short* __restrict__ Bt, int bn, int K,
    f32x4 acc[2][2], unsigned short* As, unsigned short* Bs){
  const int t = threadIdx.x;
  const int lane = t & 63, wave = t >> 6;
  const int wr = wave >> 1, wc = wave & 1;
  const int m16 = lane & 15, quad = lane >> 4;
  for (int kc = 0; kc < K; kc += 64){
    for (int idx = t; idx < 512; idx += 256){
      int row = idx >> 3, off = (idx & 7) * 8;
      int ga = bm + row;
      ulonglong2 av = {0ull, 0ull};
      if (ga < arows) av = *(const ulonglong2*)(A + (size_t)ga * K + kc + off);
      *(ulonglong2*)(As + row * 72 + off) = av;
      ulonglong2 bv = *(const ulonglong2*)(Bt + (size_t)(bn + row) * K + kc + off);
      *(ulonglong2*)(Bs + row * 72 + off) = bv;
    }
    __syncthreads();
#pragma unroll
    for (int k2 = 0; k2 < 64; k2 += 32){
      bf16x8 a0 = *(const bf16x8*)(As + (wr * 32 + m16) * 72 + k2 + quad * 8);
      bf16x8 a1 = *(const bf16x8*)(As + (wr * 32 + 16 + m16) * 72 + k2 + quad * 8);
      bf16x8 b0 = *(const bf16x8*)(Bs + (wc * 32 + m16) * 72 + k2 + quad * 8);
      bf16x8 b1 = *(const bf16x8*)(Bs + (wc * 32 + 16 + m16) * 72 + k2 + quad * 8);
      acc[0][0] = __builtin_amdgcn_mfma_f32_16x16x32_bf16(a0, b0, acc[0][0], 0, 0, 0);
      acc[0][1] = __builtin_amdgcn_mfma_f32_16x16x32_bf16(a0, b1, acc[0][1], 0, 0, 0);
      acc[1][0] = __builtin_amdgcn_mfma_f32_16x16x32_bf16(a1, b0, acc[1][0], 0, 0, 0);
      acc[1][1] = __builtin_amdgcn_mfma_f32_16x16x32_bf16(a1, b1, acc[1][1], 0, 0, 0);
    }
    __syncthreads();
  }
}

// ---------------- fc1 ----------------
__global__ __launch_bounds__(256) void fc1_mfma_kernel(
    const unsigned short* __restrict__ Ah, const unsigned short* __restrict__ Bt,
    const float* __restrict__ bias, float* __restrict__ h){
  __shared__ unsigned short As[64 * 72], Bs[64 * 72];
  f32x4 z4 = {0.f, 0.f, 0.f, 0.f};
  f32x4 acc[2][2] = {{z4, z4}, {z4, z4}};
  const int bm = blockIdx.x * 64, bn = blockIdx.y * 64;
  mfma_tile64(Ah, 20480, bm, Bt, bn, E_, acc, As, Bs);
  const int lane = threadIdx.x & 63, wave = threadIdx.x >> 6;
  const int wr = wave >> 1, wc = wave & 1;
  const int m16 = lane & 15, quad = lane >> 4;
#pragma unroll
  for (int mi = 0; mi < 2; mi++)
#pragma unroll
    for (int ni = 0; ni < 2; ni++){
      int col = bn + wc * 32 + ni * 16 + m16;
      float bv = bias[col];
#pragma unroll
      for (int r = 0; r < 4; r++){
        int row = bm + wr * 32 + mi * 16 + quad * 4 + r;
        float vv = fmaxf(acc[mi][ni][r] + bv, 0.f);
        h[(size_t)(1 + row) * D_ + col] = vv;
        if (row < 256) h[(size_t)(20481 + row) * D_ + col] = vv;
      }
    }
}

__global__ void cls_kernel(const float* __restrict__ cls, float* __restrict__ h){
  int c = blockIdx.x * 256 + threadIdx.x;
  if (c < D_) h[c] = cls[c];
}

// ---------------- layernorm -> zero-padded bf16 xph ----------------
__global__ __launch_bounds__(256) void ln_pad_kernel(
    const float* __restrict__ h, const float* __restrict__ w,
    const float* __restrict__ b, unsigned short* __restrict__ xph){
  const int r = blockIdx.x;
  const int t = threadIdx.x;
  if (r < PADR){
    xph[(size_t)r * D_ + t] = 0;
    xph[(size_t)r * D_ + 256 + t] = 0;
    return;
  }
  __shared__ float s4[4];
  const float* x = h + (size_t)(r - PADR) * D_;
  float a0 = x[t], a1 = x[t + 256];
  float mu = blockSum256(a0 + a1, s4) * (1.f / 512.f);
  float d0 = a0 - mu, d1 = a1 - mu;
  float var = blockSum256(d0 * d0 + d1 * d1, s4) * (1.f / 512.f);
  float rs = rsqrtf(var + 1e-5f);
  xph[(size_t)r * D_ + t]       = f2bf(d0 * rs * w[t] + b[t]);
  xph[(size_t)r * D_ + 256 + t] = f2bf(d1 * rs * w[t + 256] + b[t + 256]);
}

// ---------------- qkv MFMA: q/k/v all bf16 head-major (q scaled 1/8) ----------
__global__ __launch_bounds__(256) void qkv_mfma_kernel(
    const unsigned short* __restrict__ A, const unsigned short* __restrict__ Bt,
    unsigned short* __restrict__ q16, unsigned short* __restrict__ k16,
    unsigned short* __restrict__ v16){
  __shared__ unsigned short As[64 * 72], Bs[64 * 72];
  f32x4 z4 = {0.f, 0.f, 0.f, 0.f};
  f32x4 acc[2][2] = {{z4, z4}, {z4, z4}};
  const int bm = blockIdx.x * 64, bn = blockIdx.y * 64;
  mfma_tile64(A, NP_, bm, Bt, bn, D_, acc, As, Bs);
  const int lane = threadIdx.x & 63, wave = threadIdx.x >> 6;
  const int wr = wave >> 1, wc = wave & 1;
  const int m16 = lane & 15, quad = lane >> 4;
#pragma unroll
  for (int mi = 0; mi < 2; mi++)
#pragma unroll
    for (int ni = 0; ni < 2; ni++){
      int col = bn + wc * 32 + ni * 16 + m16;
      int which = col >> 9, hh = (col >> 6) & 7, d = col & 63;
      size_t cbase = (size_t)hh * NP_ * HD_ + d;
      unsigned short* dst;
      float sc = 1.f;
      if (which == 0){ dst = q16; sc = 0.125f; }
      else if (which == 1) dst = k16;
      else dst = v16;
#pragma unroll
      for (int r = 0; r < 4; r++){
        int row = bm + wr * 32 + mi * 16 + quad * 4 + r;
        dst[cbase + (size_t)row * HD_] = f2bf(acc[mi][ni][r] * sc);
      }
    }
}

// ---------------- landmarks: bf16 q/k -> ql/kl fp32 + qlh/klh bf16 ----------
__global__ __launch_bounds__(64) void landmark_kernel(
    const unsigned short* __restrict__ q16, const unsigned short* __restrict__ k16,
    float* __restrict__ ql, float* __restrict__ kl,
    unsigned short* __restrict__ qlh, unsigned short* __restrict__ klh){
  const int im = blockIdx.x, h = blockIdx.y, d = threadIdx.x;
  size_t base = ((size_t)h * NP_ + (size_t)im * LCH) * HD_ + d;
  float sq = 0.f, sk = 0.f;
  for (int r = 0; r < LCH; r++){
    sq += bfu(q16[base + (size_t)r * HD_]);
    sk += bfu(k16[base + (size_t)r * HD_]);
  }
  float qm = sq * (1.f / 82.f), km = sk * (1.f / 82.f);
  size_t oidx = ((size_t)h * MLM + im) * HD_ + d;
  ql[oidx] = qm;  qlh[oidx] = f2bf(qm);
  kl[oidx] = km;  klh[oidx] = f2bf(km);
}

// ---------------- a2 = softmax(ql @ kl^T) ----------------
__global__ __launch_bounds__(256) void a2_kernel(
    const float* __restrict__ ql, const float* __restrict__ kl,
    float* __restrict__ a2){
  const int im = blockIdx.x, h = blockIdx.y, t = threadIdx.x;
  __shared__ __align__(16) float qs[64];
  __shared__ float s4[4];
  if (t < 64) qs[t] = ql[((size_t)h * MLM + im) * HD_ + t];
  __syncthreads();
  const float4* kr4 = (const float4*)(kl + ((size_t)h * MLM + t) * HD_);
  const float4* qs4 = (const float4*)qs;
  float s = 0.f;
#pragma unroll
  for (int d4 = 0; d4 < 16; d4++){
    float4 kv = kr4[d4], qv = qs4[d4];
    s += qv.x*kv.x + qv.y*kv.y + qv.z*kv.z + qv.w*kv.w;
  }
  float mx = blockMax256(s, s4);
  float e = __expf(s - mx);
  float S = blockSum256(e, s4);
  a2[((size_t)h * MLM + im) * MLM + t] = e / S;
}

// ---------------- pinv: ONE cooperative kernel ----------------
// grid 128 x 256. Block blk -> (h=blk>>4, tile=blk&15; bm=(tile>>2)*64,
// bn=(tile&3)*64). Stages separated by grid.sync():
//   A: per-head row/col abs-sum maxima -> scal slots (blocks 0..7)
//   B: z0 = a2^T / (rmax*cmax)
//   6x { ta=a2@zc; tb=ta@(7I-ta); tc=ta@(15I-tb); za=0.25*zc@(13I-tc); swap }
// Final z ends in z0 (6 swaps). Split-bf16 MFMA per stage (~fp32 accuracy).
__device__ __forceinline__ void bmm_stage(
    const float* __restrict__ Ab, const float* __restrict__ Bb,
    float* __restrict__ Cb, float c0, float sgn, float c1,
    unsigned short* Ash, unsigned short* Asl,
    unsigned short* Bsh, unsigned short* Bsl){
  const int blk = blockIdx.x;
  const int h = blk >> 4, tile = blk & 15;
  const int bm = (tile >> 2) * 64, bn = (tile & 3) * 64;
  const float* A = Ab + (size_t)h * 65536;
  const float* B = Bb + (size_t)h * 65536;
  float* C = Cb + (size_t)h * 65536;
  const int t = threadIdx.x, lane = t & 63, w = t >> 6;
  const int wr = w >> 1, wc = w & 1, m16 = lane & 15, quad = lane >> 4;
  f32x4 z4 = {0.f, 0.f, 0.f, 0.f};
  f32x4 acc[2][2] = {{z4, z4}, {z4, z4}};
  for (int kc = 0; kc < 256; kc += 32){
    {
      int row = t >> 2, c8 = (t & 3) * 8;
      const float* src = A + (size_t)(bm + row) * 256 + kc + c8;
      float xs[8];
      *(float4*)(xs)     = *(const float4*)src;
      *(float4*)(xs + 4) = *(const float4*)(src + 4);
#pragma unroll
      for (int j = 0; j < 8; j++){
        unsigned short hi = f2bf(xs[j]);
        Ash[row * 40 + c8 + j] = hi;
        Asl[row * 40 + c8 + j] = f2bf(xs[j] - bfu(hi));
      }
      int k = t >> 3, n8 = (t & 7) * 8;
      const float* bsrc = B + (size_t)(kc + k) * 256 + bn + n8;
      float ys[8];
      *(float4*)(ys)     = *(const float4*)bsrc;
      *(float4*)(ys + 4) = *(const float4*)(bsrc + 4);
#pragma unroll
      for (int j = 0; j < 8; j++){
        float xv = sgn * ys[j];
        if (kc + k == bn + n8 + j) xv += c0;
        unsigned short hi = f2bf(xv);
        Bsh[(n8 + j) * 40 + k] = hi;
        Bsl[(n8 + j) * 40 + k] = f2bf(xv - bfu(hi));
      }
    }
    __syncthreads();
    bf16x8 ah[2], al[2], bh[2], bl[2];
#pragma unroll
    for (int mi = 0; mi < 2; mi++){
      ah[mi] = *(const bf16x8*)(Ash + (wr * 32 + mi * 16 + m16) * 40 + quad * 8);
      al[mi] = *(const bf16x8*)(Asl + (wr * 32 + mi * 16 + m16) * 40 + quad * 8);
      bh[mi] = *(const bf16x8*)(Bsh + (wc * 32 + mi * 16 + m16) * 40 + quad * 8);
      bl[mi] = *(const bf16x8*)(Bsl + (wc * 32 + mi * 16 + m16) * 40 + quad * 8);
    }
#pragma unroll
    for (int mi = 0; mi < 2; mi++)
#pragma unroll
      for (int ni = 0; ni < 2; ni++){
        acc[mi][ni] = __builtin_amdgcn_mfma_f32_16x16x32_bf16(ah[mi], bh[ni], acc[mi][ni], 0, 0, 0);
        acc[mi][ni] = __builtin_amdgcn_mfma_f32_16x16x32_bf16(ah[mi], bl[ni], acc[mi][ni], 0, 0, 0);
        acc[mi][ni] = __builtin_amdgcn_mfma_f32_16x16x32_bf16(al[mi], bh[ni], acc[mi][ni], 0, 0, 0);
      }
    __syncthreads();
  }
#pragma unroll
  for (int mi = 0; mi < 2; mi++)
#pragma unroll
    for (int ni = 0; ni < 2; ni++)
#pragma unroll
      for (int r = 0; r < 4; r++){
        int row = bm + wr * 32 + mi * 16 + quad * 4 + r;
        int col = bn + wc * 32 + ni * 16 + m16;
        C[(size_t)row * 256 + col] = c1 * acc[mi][ni][r];
      }
}

__global__ __launch_bounds__(256) void pinv_coop_kernel(
    const float* __restrict__ a2, float* __restrict__ z0, float* __restrict__ z1,
    float* __restrict__ ta, float* __restrict__ tb, float* __restrict__ tc,
    float* __restrict__ scal){
  __shared__ __align__(16) unsigned short Ash[64 * 40], Asl[64 * 40];
  __shared__ __align__(16) unsigned short Bsh[64 * 40], Bsl[64 * 40];
  cg::grid_group grid = cg::this_grid();
  const int blk = blockIdx.x, t = threadIdx.x;

  // stage A: per-head scale maxima (blocks 0..7)
  if (blk < 8){
    const float* A = a2 + (size_t)blk * 65536;
    float rs = 0.f, cs = 0.f;
    for (int k = 0; k < 256; k++){
      rs += fabsf(A[(size_t)t * 256 + k]);
      cs += fabsf(A[(size_t)k * 256 + t]);
    }
    float* sb = (float*)Ash;
    float rmax = blockMax256(rs, sb);
    float cmax = blockMax256(cs, sb);
    if (t == 0){ scal[blk * 2] = rmax; scal[blk * 2 + 1] = cmax; }
  }
  grid.sync();
  // stage B: z0 = a2^T / (rmax*cmax)
  {
    float rmax = scal[0], cmax = scal[1];
#pragma unroll
    for (int h = 1; h < 8; h++){
      rmax = fmaxf(rmax, scal[h * 2]);
      cmax = fmaxf(cmax, scal[h * 2 + 1]);
    }
    float inv = 1.f / (rmax * cmax);
    int h = blk >> 4, t16 = blk & 15;
    const float* A = a2 + (size_t)h * 65536;
    float* Z = z0 + (size_t)h * 65536;
    for (int idx = t; idx < 4096; idx += 256){
      int i = t16 * 16 + (idx >> 8);
      int j = idx & 255;
      Z[(size_t)i * 256 + j] = A[(size_t)j * 256 + i] * inv;
    }
  }
  grid.sync();
  float* zc = z0; float* za = z1;
  for (int it = 0; it < 6; it++){
    bmm_stage(a2, zc, ta, 0.f, 1.f, 1.f, Ash, Asl, Bsh, Bsl);   grid.sync();
    bmm_stage(ta, ta, tb, 7.f, -1.f, 1.f, Ash, Asl, Bsh, Bsl);  grid.sync();
    bmm_stage(ta, tb, tc, 15.f, -1.f, 1.f, Ash, Asl, Bsh, Bsl); grid.sync();
    bmm_stage(zc, tc, za, 13.f, -1.f, 0.25f, Ash, Asl, Bsh, Bsl);
    float* tmp = zc; zc = za; za = tmp;
    if (it < 5) grid.sync();
  }
}

// ---------------- a3v split-K flash, bf16 MFMA ----------------
__global__ __launch_bounds__(256) void a3v_part_kernel(
    const unsigned short* __restrict__ qlh, const unsigned short* __restrict__ k16,
    const unsigned short* __restrict__ v16, float* __restrict__ pacc,
    float* __restrict__ pml){
  __shared__ __align__(16) unsigned short qs16[64 * 72];
  __shared__ __align__(16) unsigned short kb16[64 * 72];   // K, then P
  __shared__ __align__(16) unsigned short vt16[64 * 72];   // V^T [d][n]
  const int lt = blockIdx.x, h = blockIdx.y, ch = blockIdx.z;
  const int t = threadIdx.x;
  const int lane = t & 63, w = t >> 6;
  const int m16 = lane & 15, quad = lane >> 4;

  const unsigned short* qg = qlh + ((size_t)h * MLM + lt * 64) * HD_;
  for (int idx = t; idx < 512; idx += 256){
    int row = idx >> 3, off = (idx & 7) * 8;
    *(uint4*)(qs16 + row * 72 + off) = *(const uint4*)(qg + (size_t)row * HD_ + off);
  }
  f32x4 z4 = {0.f, 0.f, 0.f, 0.f};
  f32x4 acc_o[4] = {z4, z4, z4, z4};
  float mreg[4], lreg[4];
#pragma unroll
  for (int r = 0; r < 4; r++){ mreg[r] = -3.0e38f; lreg[r] = 0.f; }
  const unsigned short* kg = k16 + ((size_t)h * NP_ + ch * CHTOK) * HD_;
  const unsigned short* vg = v16 + ((size_t)h * NP_ + ch * CHTOK) * HD_;

  for (int sc = 0; sc < 8; sc++){
    __syncthreads();
    for (int idx = t; idx < 512; idx += 256){
      int row = idx >> 3, off = (idx & 7) * 8;
      *(uint4*)(kb16 + row * 72 + off) =
          *(const uint4*)(kg + (size_t)(sc * 64 + row) * HD_ + off);
      uint4 pv = *(const uint4*)(vg + (size_t)(sc * 64 + row) * HD_ + off);
      unsigned int uu[4] = {pv.x, pv.y, pv.z, pv.w};
#pragma unroll
      for (int j = 0; j < 4; j++){
        vt16[(off + 2 * j)     * 72 + row] = (unsigned short)(uu[j] & 0xffffu);
        vt16[(off + 2 * j + 1) * 72 + row] = (unsigned short)(uu[j] >> 16);
      }
    }
    __syncthreads();
    f32x4 acc_s[4] = {z4, z4, z4, z4};
#pragma unroll
    for (int kc = 0; kc < 64; kc += 32){
      bf16x8 a = *(const bf16x8*)(qs16 + (w * 16 + m16) * 72 + kc + quad * 8);
#pragma unroll
      for (int ni = 0; ni < 4; ni++){
        bf16x8 b = *(const bf16x8*)(kb16 + (ni * 16 + m16) * 72 + kc + quad * 8);
        acc_s[ni] = __builtin_amdgcn_mfma_f32_16x16x32_bf16(a, b, acc_s[ni], 0, 0, 0);
      }
    }
    __syncthreads();
#pragma unroll
    for (int r = 0; r < 4; r++){
      float cm = fmaxf(fmaxf(acc_s[0][r], acc_s[1][r]), fmaxf(acc_s[2][r], acc_s[3][r]));
#pragma unroll
      for (int o = 1; o < 16; o <<= 1) cm = fmaxf(cm, __shfl_xor(cm, o));
      float mn = fmaxf(mreg[r], cm);
      float scl = __expf(mreg[r] - mn);
      float p0 = __expf(acc_s[0][r] - mn), p1 = __expf(acc_s[1][r] - mn);
      float p2 = __expf(acc_s[2][r] - mn), p3 = __expf(acc_s[3][r] - mn);
      float ls = (p0 + p1) + (p2 + p3);
#pragma unroll
      for (int o = 1; o < 16; o <<= 1) ls += __shfl_xor(ls, o);
      lreg[r] = lreg[r] * scl + ls;
      mreg[r] = mn;
      acc_o[0][r] *= scl; acc_o[1][r] *= scl;
      acc_o[2][r] *= scl; acc_o[3][r] *= scl;
      int prow = (w * 16 + quad * 4 + r) * 72 + m16;
      kb16[prow + 0]  = f2bf(p0);
      kb16[prow + 16] = f2bf(p1);
      kb16[prow + 32] = f2bf(p2);
      kb16[prow + 48] = f2bf(p3);
    }
    __syncthreads();
#pragma unroll
    for (int kc = 0; kc < 64; kc += 32){
      bf16x8 a = *(const bf16x8*)(kb16 + (w * 16 + m16) * 72 + kc + quad * 8);
#pragma unroll
      for (int ni = 0; ni < 4; ni++){
        bf16x8 b = *(const bf16x8*)(vt16 + (ni * 16 + m16) * 72 + kc + quad * 8);
        acc_o[ni] = __builtin_amdgcn_mfma_f32_16x16x32_bf16(a, b, acc_o[ni], 0, 0, 0);
      }
    }
  }
#pragma unroll
  for (int r = 0; r < 4; r++){
    int im = lt * 64 + w * 16 + quad * 4 + r;
    size_t base = ((size_t)h * NCH + ch) * MLM + im;
#pragma unroll
    for (int ni = 0; ni < 4; ni++)
      pacc[base * HD_ + ni * 16 + m16] = acc_o[ni][r];
    if (m16 == 0){
      pml[base * 2]     = mreg[r];
      pml[base * 2 + 1] = lreg[r];
    }
  }
}

__global__ __launch_bounds__(64) void a3v_combine_kernel(
    const float* __restrict__ pacc, const float* __restrict__ pml,
    float* __restrict__ t1){
  const int im = blockIdx.x, h = blockIdx.y, lane = threadIdx.x;
  float M = -3.0e38f;
  for (int c = 0; c < NCH; c++)
    M = fmaxf(M, pml[(((size_t)h * NCH + c) * MLM + im) * 2]);
  float accv = 0.f, L = 0.f;
  for (int c = 0; c < NCH; c++){
    size_t base = ((size_t)h * NCH + c) * MLM + im;
    float mc = pml[base * 2], lc = pml[base * 2 + 1];
    float w = __expf(mc - M);
    accv += w * pacc[base * HD_ + lane];
    L += w * lc;
  }
  t1[((size_t)h * MLM + im) * HD_ + lane] = accv / L;
}

// ---------------- t2^T = (z @ t1)^T, bf16 [h][d][im] ----------------
__global__ __launch_bounds__(256) void zt1_kernel(
    const float* __restrict__ z, const float* __restrict__ t1,
    unsigned short* __restrict__ t2t){
  const int h = blockIdx.y;
  const int t = threadIdx.x;
  const int d = t & 63, ri = t >> 6;
  const int im = blockIdx.x * 4 + ri;
  const float* zr = z + ((size_t)h * MLM + im) * MLM;
  const float* t1h = t1 + (size_t)h * MLM * HD_;
  float acc = 0.f;
#pragma unroll 8
  for (int kk = 0; kk < MLM; kk++) acc += zr[kk] * t1h[(size_t)kk * HD_ + d];
  t2t[((size_t)h * HD_ + d) * MLM + im] = f2bf(acc);
}

// ---------------- out tile MFMA: 64 tokens x 1 head per block ----------------
__global__ __launch_bounds__(256) void out_tile_kernel(
    const unsigned short* __restrict__ q16, const unsigned short* __restrict__ klh,
    const unsigned short* __restrict__ t2t, const unsigned short* __restrict__ v16,
    const float* __restrict__ resw, unsigned short* __restrict__ outh){
  __shared__ __align__(16) unsigned short smem[64 * 72 * 2 + 64 * 264];
  unsigned short* qs16 = smem;                 // 64 x 72
  unsigned short* kb16 = smem + 64 * 72;       // 64 x 72 (kl chunks, t2t chunks)
  unsigned short* Ps   = smem + 64 * 72 * 2;   // 64 x 264 (P bf16; later O f32 + v tile)
  const int tile = blockIdx.x, h = blockIdx.y;
  const int n0 = PADR + tile * 64;
  const int t = threadIdx.x;
  const int lane = t & 63, w = t >> 6;
  const int m16 = lane & 15, quad = lane >> 4;

  {
    const unsigned short* qh = q16 + (size_t)h * NP_ * HD_;
    for (int idx = t; idx < 512; idx += 256){
      int row = idx >> 3, off = (idx & 7) * 8;
      int n = n0 + row;
      uint4 val = {0u, 0u, 0u, 0u};
      if (n < NP_) val = *(const uint4*)(qh + (size_t)n * HD_ + off);
      *(uint4*)(qs16 + row * 72 + off) = val;
    }
  }
  f32x4 z4 = {0.f, 0.f, 0.f, 0.f};
  f32x4 acc_s[16];
#pragma unroll
  for (int i = 0; i < 16; i++) acc_s[i] = z4;
  const unsigned short* klg = klh + (size_t)h * MLM * HD_;
  for (int m = 0; m < 4; m++){
    __syncthreads();
    for (int idx = t; idx < 512; idx += 256){
      int row = idx >> 3, off = (idx & 7) * 8;
      *(uint4*)(kb16 + row * 72 + off) =
          *(const uint4*)(klg + (size_t)(m * 64 + row) * HD_ + off);
    }
    __syncthreads();
#pragma unroll
    for (int kc = 0; kc < 64; kc += 32){
      bf16x8 a = *(const bf16x8*)(qs16 + (w * 16 + m16) * 72 + kc + quad * 8);
#pragma unroll
      for (int ni = 0; ni < 4; ni++){
        bf16x8 b = *(const bf16x8*)(kb16 + (ni * 16 + m16) * 72 + kc + quad * 8);
        acc_s[m * 4 + ni] = __builtin_amdgcn_mfma_f32_16x16x32_bf16(a, b, acc_s[m * 4 + ni], 0, 0, 0);
      }
    }
  }
  __syncthreads();
#pragma unroll
  for (int r = 0; r < 4; r++){
    float mx = acc_s[0][r];
#pragma unroll
    for (int mc = 1; mc < 16; mc++) mx = fmaxf(mx, acc_s[mc][r]);
#pragma unroll
    for (int o = 1; o < 16; o <<= 1) mx = fmaxf(mx, __shfl_xor(mx, o));
    float p[16]; float sum = 0.f;
#pragma unroll
    for (int mc = 0; mc < 16; mc++){ p[mc] = __expf(acc_s[mc][r] - mx); sum += p[mc]; }
#pragma unroll
    for (int o = 1; o < 16; o <<= 1) sum += __shfl_xor(sum, o);
    float inv = 1.f / sum;
    int prow = (w * 16 + quad * 4 + r) * 264;
#pragma unroll
    for (int mc = 0; mc < 16; mc++)
      Ps[prow + (mc >> 2) * 64 + (mc & 3) * 16 + m16] = f2bf(p[mc] * inv);
  }
  f32x4 acc_o[4] = {z4, z4, z4, z4};
  const unsigned short* t2g = t2t + (size_t)h * HD_ * MLM;
  for (int ch = 0; ch < 4; ch++){
    __syncthreads();
    {
      int row = t >> 2, c8 = (t & 3) * 16;
      const unsigned short* src = t2g + (size_t)row * MLM + ch * 64 + c8;
      *(uint4*)(kb16 + row * 72 + c8)     = *(const uint4*)src;
      *(uint4*)(kb16 + row * 72 + c8 + 8) = *(const uint4*)(src + 8);
    }
    __syncthreads();
#pragma unroll
    for (int kc = 0; kc < 64; kc += 32){
      bf16x8 a = *(const bf16x8*)(Ps + (w * 16 + m16) * 264 + ch * 64 + kc + quad * 8);
#pragma unroll
      for (int ni = 0; ni < 4; ni++){
        bf16x8 b = *(const bf16x8*)(kb16 + (ni * 16 + m16) * 72 + kc + quad * 8);
        acc_o[ni] = __builtin_amdgcn_mfma_f32_16x16x32_bf16(a, b, acc_o[ni], 0, 0, 0);
      }
    }
  }
  __syncthreads();
  float* Obuf = (float*)Ps;                          // 64 x 66 f32
  unsigned short* vtile = (unsigned short*)(Obuf + 64 * 66);  // 96 x 72 bf16
#pragma unroll
  for (int r = 0; r < 4; r++){
    int row = w * 16 + quad * 4 + r;
#pragma unroll
    for (int ni = 0; ni < 4; ni++)
      Obuf[row * 66 + ni * 16 + m16] = acc_o[ni][r];
  }
  {
    const unsigned short* vh = v16 + (size_t)h * NP_ * HD_;
    for (int idx = t; idx < 768; idx += 256){
      int row = idx >> 3, off = (idx & 7) * 8;
      int nn = n0 - 16 + row;
      uint4 val = {0u, 0u, 0u, 0u};
      if (nn < NP_) val = *(const uint4*)(vh + (size_t)nn * HD_ + off);
      *(uint4*)(vtile + row * 72 + off) = val;
    }
  }
  __syncthreads();
  float wreg[33];
  {
    const float* wr = resw + h * 33;
#pragma unroll
    for (int kk = 0; kk < 33; kk++) wreg[kk] = wr[kk];
  }
  const int ty = t >> 4, tx = t & 15;
#pragma unroll
  for (int i = 0; i < 4; i++){
    int lrow = ty * 4 + i;
    float c0v = 0.f, c1v = 0.f, c2v = 0.f, c3v = 0.f;
    for (int kk = 0; kk < 33; kk++){
      uint2 uv = *(const uint2*)(vtile + (lrow + kk) * 72 + tx * 4);
      float wv = wreg[kk];
      c0v += __uint_as_float(uv.x << 16) * wv;
      c1v += __uint_as_float(uv.x & 0xffff0000u) * wv;
      c2v += __uint_as_float(uv.y << 16) * wv;
      c3v += __uint_as_float(uv.y & 0xffff0000u) * wv;
    }
    int trow = tile * 64 + lrow;
    if (trow < NTOK){
      const float* orow = Obuf + lrow * 66 + tx * 4;
      unsigned long long pk =
          (unsigned long long)f2bf(orow[0] + c0v)
        | ((unsigned long long)f2bf(orow[1] + c1v) << 16)
        | ((unsigned long long)f2bf(orow[2] + c2v) << 32)
        | ((unsigned long long)f2bf(orow[3] + c3v) << 48);
      *(unsigned long long*)(outh + (size_t)trow * D_ + h * HD_ + tx * 4) = pk;
    }
  }
}

// ---------------- proj MFMA: h += outh @ out_wt^T + bias ----------------
__global__ __launch_bounds__(256) void proj_mfma_kernel(
    const unsigned short* __restrict__ A, const unsigned short* __restrict__ Bt,
    const float* __restrict__ bias, float* __restrict__ h){
  __shared__ unsigned short As[64 * 72], Bs[64 * 72];
  f32x4 z4 = {0.f, 0.f, 0.f, 0.f};
  f32x4 acc[2][2] = {{z4, z4}, {z4, z4}};
  const int bm = blockIdx.x * 64, bn = blockIdx.y * 64;
  mfma_tile64(A, NTOK, bm, Bt, bn, D_, acc, As, Bs);
  const int lane = threadIdx.x & 63, wave = threadIdx.x >> 6;
  const int wr = wave >> 1, wc = wave & 1;
  const int m16 = lane & 15, quad = lane >> 4;
#pragma unroll
  for (int mi = 0; mi < 2; mi++)
#pragma unroll
    for (int ni = 0; ni < 2; ni++){
      int col = bn + wc * 32 + ni * 16 + m16;
      float bv = bias[col];
#pragma unroll
      for (int r = 0; r < 4; r++){
        int row = bm + wr * 32 + mi * 16 + quad * 4 + r;
        if (row < NTOK) h[(size_t)row * D_ + col] += acc[mi][ni][r] + bv;
      }
    }
}

// ---------------- PPEG ----------------
__global__ __launch_bounds__(512) void ppeg_combine_kernel(
    const float* __restrict__ w7, const float* __restrict__ b7,
    const float* __restrict__ w5, const float* __restrict__ b5,
    const float* __restrict__ w3, const float* __restrict__ b3,
    float* __restrict__ wcomb, float* __restrict__ bcomb){
  const int c = threadIdx.x;
#pragma unroll
  for (int i = 0; i < 7; i++){
#pragma unroll
    for (int j = 0; j < 7; j++){
      int di = i - 3, dj = j - 3;
      float wv = w7[(size_t)c * 49 + i * 7 + j];
      if (di >= -2 && di <= 2 && dj >= -2 && dj <= 2)
        wv += w5[(size_t)c * 25 + (di + 2) * 5 + (dj + 2)];
      if (di >= -1 && di <= 1 && dj >= -1 && dj <= 1)
        wv += w3[(size_t)c * 9 + (di + 1) * 3 + (dj + 1)];
      if (di == 0 && dj == 0) wv += 1.f;
      wcomb[(size_t)(i * 7 + j) * 512 + c] = wv;
    }
  }
  bcomb[c] = b7[c] + b5[c] + b3[c];
}

__global__ __launch_bounds__(512) void ppeg_conv_kernel(
    const float* __restrict__ h, const float* __restrict__ wcomb,
    const float* __restrict__ bcomb, float* __restrict__ tmp){
  const int c = threadIdx.x;
  const int y = blockIdx.y;
  const int x0 = blockIdx.x * 8;
  float wc[49];
#pragma unroll
  for (int kk = 0; kk < 49; kk++) wc[kk] = wcomb[(size_t)kk * 512 + c];
  float acc[8];
  const float bv = bcomb[c];
#pragma unroll
  for (int p = 0; p < 8; p++) acc[p] = bv;
#pragma unroll
  for (int i = 0; i < 7; i++){
    const int yy = y + i - 3;
    if (yy < 0 || yy >= HHW) continue;
    const float* hrow = h + (size_t)(1 + yy * HHW) * D_ + c;
    float line[14];
#pragma unroll
    for (int j = 0; j < 14; j++){
      const int xx = x0 + j - 3;
      line[j] = (xx >= 0 && xx < HHW) ? hrow[(size_t)xx * D_] : 0.f;
    }
#pragma unroll
    for (int p = 0; p < 8; p++)
#pragma unroll
      for (int j = 0; j < 7; j++)
        acc[p] += line[p + j] * wc[i * 7 + j];
  }
#pragma unroll
  for (int p = 0; p < 8; p++)
    tmp[(size_t)(y * HHW + x0 + p) * D_ + c] = acc[p];
}

__global__ void ppeg_copy_kernel(const float* __restrict__ tmp, float* __restrict__ h){
  size_t idx = (size_t)blockIdx.x * 256 + threadIdx.x;
  if (idx < (size_t)NFEAT * D_) h[idx + D_] = tmp[idx];
}

// ---------------- final ----------------
__global__ __launch_bounds__(512) void final_kernel(
    const float* __restrict__ h, const float* __restrict__ w,
    const float* __restrict__ b, const float* __restrict__ fc3w,
    const float* __restrict__ fc3b, float* __restrict__ out){
  __shared__ float vec[512];
  __shared__ float s8[8];
  __shared__ float lg[4];
  const int t = threadIdx.x;
  float x = h[t];
  float v = waveSumF(x);
  if ((t & 63) == 0) s8[t >> 6] = v;
  __syncthreads();
  float sum = 0.f;
#pragma unroll
  for (int i = 0; i < 8; i++) sum += s8[i];
  float mu = sum * (1.f / 512.f);
  __syncthreads();
  float d = x - mu;
  v = waveSumF(d * d);
  if ((t & 63) == 0) s8[t >> 6] = v;
  __syncthreads();
  float var = 0.f;
#pragma unroll
  for (int i = 0; i < 8; i++) var += s8[i];
  var *= (1.f / 512.f);
  float rs = rsqrtf(var + 1e-5f);
  vec[t] = d * rs * w[t] + b[t];
  __syncthreads();
  if (t < 4){
    float acc = fc3b[t];
    for (int kk = 0; kk < 512; kk++) acc += vec[kk] * fc3w[kk * 4 + t];
    lg[t] = acc;
  }
  __syncthreads();
  if (t == 0){
    float m = fmaxf(fmaxf(lg[0], lg[1]), fmaxf(lg[2], lg[3]));
    float e[4], se = 0.f;
#pragma unroll
    for (int i = 0; i < 4; i++){ e[i] = __expf(lg[i] - m); se += e[i]; }
    int am = 0; float bm = lg[0];
#pragma unroll
    for (int i = 1; i < 4; i++) if (lg[i] > bm){ bm = lg[i]; am = i; }
#pragma unroll
    for (int i = 0; i < 4; i++){ out[i] = lg[i]; out[4 + i] = e[i] / se; }
    out[8] = (float)am;
  }
}

// ---------------------------------------------------------------------------
extern "C" void kernel_launch(void* const* d_in, const int* in_sizes, int n_in,
                              void* d_out, int out_size, void* d_ws, size_t ws_size,
                              hipStream_t stream) {
  const float* x       = (const float*)d_in[0];
  const float* fc1_w   = (const float*)d_in[1];
  const float* fc1_b   = (const float*)d_in[2];
  const float* cls_tok = (const float*)d_in[3];
  const float* l1_nw   = (const float*)d_in[4];
  const float* l1_nb   = (const float*)d_in[5];
  const float* l1_qkvw = (const float*)d_in[6];
  const float* l1_outw = (const float*)d_in[7];
  const float* l1_outb = (const float*)d_in[8];
  const float* l1_resw = (const float*)d_in[9];
  const float* ppeg_w7 = (const float*)d_in[10];
  const float* ppeg_b7 = (const float*)d_in[11];
  const float* ppeg_w5 = (const float*)d_in[12];
  const float* ppeg_b5 = (const float*)d_in[13];
  const float* ppeg_w3 = (const float*)d_in[14];
  const float* ppeg_b3 = (const float*)d_in[15];
  const float* l2_nw   = (const float*)d_in[16];
  const float* l2_nb   = (const float*)d_in[17];
  const float* l2_qkvw = (const float*)d_in[18];
  const float* l2_outw = (const float*)d_in[19];
  const float* l2_outb = (const float*)d_in[20];
  const float* l2_resw = (const float*)d_in[21];
  const float* norm_w  = (const float*)d_in[22];
  const float* norm_b  = (const float*)d_in[23];
  const float* fc3_w   = (const float*)d_in[24];
  const float* fc3_b   = (const float*)d_in[25];

  // workspace layout (float units)
  float* W = (float*)d_ws;
  size_t o = 0;
  float* hbuf = W + o; o += (size_t)NTOK * D_;
  float* xp   = W + o; o += (size_t)NP_ * D_;   // xph / pacc+pml / outh / ppeg tmp
  float* qb   = W + o; o += (size_t)NH_ * NP_ * HD_;   // bf16 q; also Ah pre-layer
  float* kb   = W + o; o += (size_t)NH_ * NP_ * HD_;   // bf16 k
  float* vb   = W + o; o += (size_t)NH_ * NP_ * HD_;   // bf16 v
  float* qlb  = W + o; o += (size_t)NH_ * MLM * HD_;
  float* klb  = W + o; o += (size_t)NH_ * MLM * HD_;
  float* a2b  = W + o; o += (size_t)NH_ * MLM * MLM;
  float* z0   = W + o; o += (size_t)NH_ * MLM * MLM;
  float* z1   = W + o; o += (size_t)NH_ * MLM * MLM;
  float* ta   = W + o; o += (size_t)NH_ * MLM * MLM;
  float* tb   = W + o; o += (size_t)NH_ * MLM * MLM;
  float* tc   = W + o; o += (size_t)NH_ * MLM * MLM;
  float* t1b  = W + o; o += (size_t)NH_ * MLM * HD_;
  float* t2r  = W + o; o += (size_t)NH_ * MLM * HD_;   // t2t bf16 lives here
  float* scalf = W + o; o += 16;
  float* wcomb = W + o; o += 49 * 512;
  float* bcomb = W + o; o += 512;
  unsigned short* fc1_wt  = (unsigned short*)(W + o); o += (size_t)D_ * E_ / 2;
  unsigned short* qkv_wt1 = (unsigned short*)(W + o); o += (size_t)1536 * D_ / 2;
  unsigned short* qkv_wt2 = (unsigned short*)(W + o); o += (size_t)1536 * D_ / 2;
  unsigned short* out_wt1 = (unsigned short*)(W + o); o += (size_t)D_ * D_ / 2;
  unsigned short* out_wt2 = (unsigned short*)(W + o); o += (size_t)D_ * D_ / 2;
  unsigned short* qlh = (unsigned short*)(W + o); o += (size_t)NH_ * MLM * HD_ / 2;
  unsigned short* klh = (unsigned short*)(W + o); o += (size_t)NH_ * MLM * HD_ / 2;

  unsigned short* xph = (unsigned short*)xp;
  float* pacc = xp;
  float* pml  = xp + (size_t)NH_ * NCH * MLM * HD_;
  unsigned short* outh = (unsigned short*)xp;
  unsigned short* Ah  = (unsigned short*)qb;
  unsigned short* q16 = (unsigned short*)qb;
  unsigned short* k16 = (unsigned short*)kb;
  unsigned short* v16 = (unsigned short*)vb;
  unsigned short* t2t = (unsigned short*)t2r;

  // ---- weight prep (once per launch) ----
  wtrans_kernel<<<dim3(E_ / 32, D_ / 32), dim3(32, 8), 0, stream>>>(fc1_w, fc1_wt, E_, D_);
  wtrans_kernel<<<dim3(D_ / 32, 1536 / 32), dim3(32, 8), 0, stream>>>(l1_qkvw, qkv_wt1, D_, 1536);
  wtrans_kernel<<<dim3(D_ / 32, 1536 / 32), dim3(32, 8), 0, stream>>>(l2_qkvw, qkv_wt2, D_, 1536);
  wtrans_kernel<<<dim3(D_ / 32, D_ / 32), dim3(32, 8), 0, stream>>>(l1_outw, out_wt1, D_, D_);
  wtrans_kernel<<<dim3(D_ / 32, D_ / 32), dim3(32, 8), 0, stream>>>(l2_outw, out_wt2, D_, D_);
  ppeg_combine_kernel<<<1, 512, 0, stream>>>(ppeg_w7, ppeg_b7, ppeg_w5, ppeg_b5,
                                             ppeg_w3, ppeg_b3, wcomb, bcomb);

  // ---- fc1 (maxpool -> bf16 -> MFMA) ----
  pool_bf16_kernel<<<20480, 256, 0, stream>>>(x, Ah);
  fc1_mfma_kernel<<<dim3(320, 8), 256, 0, stream>>>(Ah, fc1_wt, fc1_b, hbuf);
  cls_kernel<<<2, 256, 0, stream>>>(cls_tok, hbuf);

  auto run_layer = [&](const float* nw, const float* nb,
                       const unsigned short* qkvwt, const unsigned short* outwt,
                       const float* outb, const float* resw){
    ln_pad_kernel<<<NP_, 256, 0, stream>>>(hbuf, nw, nb, xph);
    qkv_mfma_kernel<<<dim3(328, 24), 256, 0, stream>>>(xph, qkvwt, q16, k16, v16);
    landmark_kernel<<<dim3(256, 8), 64, 0, stream>>>(q16, k16, qlb, klb, qlh, klh);
    a2_kernel<<<dim3(256, 8), 256, 0, stream>>>(qlb, klb, a2b);
    // fused pinv: scale + init + 6x Newton-Schulz, one cooperative launch.
    {
      void* args[] = {(void*)&a2b, (void*)&z0, (void*)&z1,
                      (void*)&ta, (void*)&tb, (void*)&tc, (void*)&scalf};
      hipLaunchCooperativeKernel((void*)pinv_coop_kernel, dim3(128), dim3(256),
                                 args, 0, stream);
    }
    a3v_part_kernel<<<dim3(4, 8, NCH), 256, 0, stream>>>(qlh, k16, v16, pacc, pml);
    a3v_combine_kernel<<<dim3(256, 8), 64, 0, stream>>>(pacc, pml, t1b);
    zt1_kernel<<<dim3(64, 8), 256, 0, stream>>>(z0, t1b, t2t);   // final z is z0
    out_tile_kernel<<<dim3(325, 8), 256, 0, stream>>>(q16, klh, t2t, v16, resw, outh);
    proj_mfma_kernel<<<dim3(325, 8), 256, 0, stream>>>(outh, outwt, outb, hbuf);
  };

  run_layer(l1_nw, l1_nb, qkv_wt1, out_wt1, l1_outb, l1_resw);
  ppeg_conv_kernel<<<dim3(HHW / 8, HHW), 512, 0, stream>>>(hbuf, wcomb, bcomb, xp);
  ppeg_copy_kernel<<<(NFEAT * D_ + 255) / 256, 256, 0, stream>>>(xp, hbuf);
  run_layer(l2_nw, l2_nb, qkv_wt2, out_wt2, l2_outb, l2_resw);
  final_kernel<<<1, 512, 0, stream>>>(hbuf, norm_w, norm_b, fc3_w, fc3_b, (float*)d_out);
}

// Round 9
// 1702.690 us; speedup vs baseline: 1.4680x; 1.4680x over previous
//
#include <hip/hip_runtime.h>

// ---------------------------------------------------------------------------
// TransMIL forward on MI355X.
//   r0: 12995 us baseline (all-fp32, classic 64x64 tiled GEMMs).
//   r1: 10182 us — PPEG collapsed to one combined 7x7 depthwise conv.
//   r2:  8278 us — out_kernel rewritten as fused 32-token tile kernel.
//   r3:  5546 us — a3v rewritten as split-K flash attention.
//   r4:  3723 us — fc1/qkv/proj GEMMs -> bf16 MFMA (16x16x32).
//   r5:  3025 us — a3v_part -> bf16 MFMA flash.
//   r6:  1735 us — out_tile -> bf16 MFMA; bmm256 -> split-bf16 MFMA.
//   r7/r8: 2500 us — REGRESSION: cooperative pinv (grid.sync ~25us each!).
//       Kept from r8: GEMM tile core BK=64 (~-310 us on fc1/qkv/proj).
//   r9: pinv back to discrete bmm256_mfma launches (24/layer); scale/init
//       slimmed to 2 launches (per-head slots, no atomics).
// ---------------------------------------------------------------------------

constexpr int D_    = 512;
constexpr int E_    = 1024;
constexpr int NTOK  = 20737;
constexpr int NP_   = 20992;   // padded seq len (255 zero rows at FRONT)
constexpr int NH_   = 8;
constexpr int HD_   = 64;
constexpr int MLM   = 256;     // landmarks
constexpr int LCH   = 82;      // tokens per landmark
constexpr int HHW   = 144;
constexpr int NFEAT = 20736;   // 144*144
constexpr int PADR  = 255;
constexpr int NCH   = 41;      // a3v N-chunks
constexpr int CHTOK = 512;     // tokens per chunk (8 subchunks of 64)

typedef __attribute__((ext_vector_type(8))) short bf16x8;
typedef __attribute__((ext_vector_type(4))) float f32x4;

__device__ __forceinline__ unsigned short f2bf(float f){
  unsigned int u = __float_as_uint(f);
  unsigned int r = u + 0x7fffu + ((u >> 16) & 1u);
  return (unsigned short)(r >> 16);
}
__device__ __forceinline__ float bfu(unsigned short u){
  return __uint_as_float((unsigned int)u << 16);
}

// ---------------- reduction helpers ----------------
__device__ __forceinline__ float waveMaxF(float v){
#pragma unroll
  for (int o = 32; o > 0; o >>= 1) v = fmaxf(v, __shfl_xor(v, o));
  return v;
}
__device__ __forceinline__ float waveSumF(float v){
#pragma unroll
  for (int o = 32; o > 0; o >>= 1) v += __shfl_xor(v, o);
  return v;
}
__device__ __forceinline__ float blockMax256(float v, float* sbuf){
  v = waveMaxF(v);
  if ((threadIdx.x & 63) == 0) sbuf[threadIdx.x >> 6] = v;
  __syncthreads();
  float r = fmaxf(fmaxf(sbuf[0], sbuf[1]), fmaxf(sbuf[2], sbuf[3]));
  __syncthreads();
  return r;
}
__device__ __forceinline__ float blockSum256(float v, float* sbuf){
  v = waveSumF(v);
  if ((threadIdx.x & 63) == 0) sbuf[threadIdx.x >> 6] = v;
  __syncthreads();
  float r = sbuf[0] + sbuf[1] + sbuf[2] + sbuf[3];
  __syncthreads();
  return r;
}

// ---------------- weight prep: W[K][N] fp32 -> Wt[N][K] bf16 ----------------
__global__ __launch_bounds__(256) void wtrans_kernel(
    const float* __restrict__ W, unsigned short* __restrict__ Wt, int K, int N){
  __shared__ float tile[32][33];
  const int kb = blockIdx.x * 32, nb = blockIdx.y * 32;
  const int tx = threadIdx.x, ty = threadIdx.y;
  for (int i = ty; i < 32; i += 8) tile[i][tx] = W[(size_t)(kb + i) * N + nb + tx];
  __syncthreads();
  for (int i = ty; i < 32; i += 8)
    Wt[(size_t)(nb + i) * K + kb + tx] = f2bf(tile[tx][i]);
}

// ---------------- maxpool2 + bf16 ----------------
__global__ __launch_bounds__(256) void pool_bf16_kernel(
    const float* __restrict__ x, unsigned short* __restrict__ Ah){
  size_t idx4 = ((size_t)blockIdx.x * 256 + threadIdx.x) * 4;
  size_t m = idx4 >> 10, e = idx4 & 1023;
  float4 a = *(const float4*)(x + (m * 2) * E_ + e);
  float4 b = *(const float4*)(x + (m * 2 + 1) * E_ + e);
  unsigned long long pk =
      (unsigned long long)f2bf(fmaxf(a.x, b.x))
    | ((unsigned long long)f2bf(fmaxf(a.y, b.y)) << 16)
    | ((unsigned long long)f2bf(fmaxf(a.z, b.z)) << 32)
    | ((unsigned long long)f2bf(fmaxf(a.w, b.w)) << 48);
  *(unsigned long long*)(Ah + idx4) = pk;
}

// ---------------- MFMA 64x64 tile core, BK=64 (bf16 in, fp32 acc) ----------
// As/Bs: 64 rows x 72 shorts (64 data + 8 pad). 8 MFMAs per barrier pair.
__device__ __forceinline__ void mfma_tile64(
    const unsigned short* __restrict__ A, int arows, int bm,
    const unsigned short* __restrict__ Bt, int bn, int K,
    f32x4 acc[2][2], unsigned short* As, unsigned short* Bs){
  const int t = threadIdx.x;
  const int lane = t & 63, wave = t >> 6;
  const int wr = wave >> 1, wc = wave & 1;
  const int m16 = lane & 15, quad = lane >> 4;
  for (int kc = 0; kc < K; kc += 64){
    for (int idx = t; idx < 512; idx += 256){
      int row = idx >> 3, off = (idx & 7) * 8;
      int ga = bm + row;
      ulonglong2 av = {0ull, 0ull};
      if (ga < arows) av = *(const ulonglong2*)(A + (size_t)ga * K + kc + off);
      *(ulonglong2*)(As + row * 72 + off) = av;
      ulonglong2 bv = *(const ulonglong2*)(Bt + (size_t)(bn + row) * K + kc + off);
      *(ulonglong2*)(Bs + row * 72 + off) = bv;
    }
    __syncthreads();
#pragma unroll
    for (int k2 = 0; k2 < 64; k2 += 32){
      bf16x8 a0 = *(const bf16x8*)(As + (wr * 32 + m16) * 72 + k2 + quad * 8);
      bf16x8 a1 = *(const bf16x8*)(As + (wr * 32 + 16 + m16) * 72 + k2 + quad * 8);
      bf16x8 b0 = *(const bf16x8*)(Bs + (wc * 32 + m16) * 72 + k2 + quad * 8);
      bf16x8 b1 = *(const bf16x8*)(Bs + (wc * 32 + 16 + m16) * 72 + k2 + quad * 8);
      acc[0][0] = __builtin_amdgcn_mfma_f32_16x16x32_bf16(a0, b0, acc[0][0], 0, 0, 0);
      acc[0][1] = __builtin_amdgcn_mfma_f32_16x16x32_bf16(a0, b1, acc[0][1], 0, 0, 0);
      acc[1][0] = __builtin_amdgcn_mfma_f32_16x16x32_bf16(a1, b0, acc[1][0], 0, 0, 0);
      acc[1][1] = __builtin_amdgcn_mfma_f32_16x16x32_bf16(a1, b1, acc[1][1], 0, 0, 0);
    }
    __syncthreads();
  }
}

// ---------------- fc1 ----------------
__global__ __launch_bounds__(256) void fc1_mfma_kernel(
    const unsigned short* __restrict__ Ah, const unsigned short* __restrict__ Bt,
    const float* __restrict__ bias, float* __restrict__ h){
  __shared__ unsigned short As[64 * 72], Bs[64 * 72];
  f32x4 z4 = {0.f, 0.f, 0.f, 0.f};
  f32x4 acc[2][2] = {{z4, z4}, {z4, z4}};
  const int bm = blockIdx.x * 64, bn = blockIdx.y * 64;
  mfma_tile64(Ah, 20480, bm, Bt, bn, E_, acc, As, Bs);
  const int lane = threadIdx.x & 63, wave = threadIdx.x >> 6;
  const int wr = wave >> 1, wc = wave & 1;
  const int m16 = lane & 15, quad = lane >> 4;
#pragma unroll
  for (int mi = 0; mi < 2; mi++)
#pragma unroll
    for (int ni = 0; ni < 2; ni++){
      int col = bn + wc * 32 + ni * 16 + m16;
      float bv = bias[col];
#pragma unroll
      for (int r = 0; r < 4; r++){
        int row = bm + wr * 32 + mi * 16 + quad * 4 + r;
        float vv = fmaxf(acc[mi][ni][r] + bv, 0.f);
        h[(size_t)(1 + row) * D_ + col] = vv;
        if (row < 256) h[(size_t)(20481 + row) * D_ + col] = vv;
      }
    }
}

__global__ void cls_kernel(const float* __restrict__ cls, float* __restrict__ h){
  int c = blockIdx.x * 256 + threadIdx.x;
  if (c < D_) h[c] = cls[c];
}

// ---------------- layernorm -> zero-padded bf16 xph ----------------
__global__ __launch_bounds__(256) void ln_pad_kernel(
    const float* __restrict__ h, const float* __restrict__ w,
    const float* __restrict__ b, unsigned short* __restrict__ xph){
  const int r = blockIdx.x;
  const int t = threadIdx.x;
  if (r < PADR){
    xph[(size_t)r * D_ + t] = 0;
    xph[(size_t)r * D_ + 256 + t] = 0;
    return;
  }
  __shared__ float s4[4];
  const float* x = h + (size_t)(r - PADR) * D_;
  float a0 = x[t], a1 = x[t + 256];
  float mu = blockSum256(a0 + a1, s4) * (1.f / 512.f);
  float d0 = a0 - mu, d1 = a1 - mu;
  float var = blockSum256(d0 * d0 + d1 * d1, s4) * (1.f / 512.f);
  float rs = rsqrtf(var + 1e-5f);
  xph[(size_t)r * D_ + t]       = f2bf(d0 * rs * w[t] + b[t]);
  xph[(size_t)r * D_ + 256 + t] = f2bf(d1 * rs * w[t + 256] + b[t + 256]);
}

// ---------------- qkv MFMA: q/k/v all bf16 head-major (q scaled 1/8) ----------
__global__ __launch_bounds__(256) void qkv_mfma_kernel(
    const unsigned short* __restrict__ A, const unsigned short* __restrict__ Bt,
    unsigned short* __restrict__ q16, unsigned short* __restrict__ k16,
    unsigned short* __restrict__ v16){
  __shared__ unsigned short As[64 * 72], Bs[64 * 72];
  f32x4 z4 = {0.f, 0.f, 0.f, 0.f};
  f32x4 acc[2][2] = {{z4, z4}, {z4, z4}};
  const int bm = blockIdx.x * 64, bn = blockIdx.y * 64;
  mfma_tile64(A, NP_, bm, Bt, bn, D_, acc, As, Bs);
  const int lane = threadIdx.x & 63, wave = threadIdx.x >> 6;
  const int wr = wave >> 1, wc = wave & 1;
  const int m16 = lane & 15, quad = lane >> 4;
#pragma unroll
  for (int mi = 0; mi < 2; mi++)
#pragma unroll
    for (int ni = 0; ni < 2; ni++){
      int col = bn + wc * 32 + ni * 16 + m16;
      int which = col >> 9, hh = (col >> 6) & 7, d = col & 63;
      size_t cbase = (size_t)hh * NP_ * HD_ + d;
      unsigned short* dst;
      float sc = 1.f;
      if (which == 0){ dst = q16; sc = 0.125f; }
      else if (which == 1) dst = k16;
      else dst = v16;
#pragma unroll
      for (int r = 0; r < 4; r++){
        int row = bm + wr * 32 + mi * 16 + quad * 4 + r;
        dst[cbase + (size_t)row * HD_] = f2bf(acc[mi][ni][r] * sc);
      }
    }
}

// ---------------- landmarks: bf16 q/k -> ql/kl fp32 + qlh/klh bf16 ----------
__global__ __launch_bounds__(64) void landmark_kernel(
    const unsigned short* __restrict__ q16, const unsigned short* __restrict__ k16,
    float* __restrict__ ql, float* __restrict__ kl,
    unsigned short* __restrict__ qlh, unsigned short* __restrict__ klh){
  const int im = blockIdx.x, h = blockIdx.y, d = threadIdx.x;
  size_t base = ((size_t)h * NP_ + (size_t)im * LCH) * HD_ + d;
  float sq = 0.f, sk = 0.f;
  for (int r = 0; r < LCH; r++){
    sq += bfu(q16[base + (size_t)r * HD_]);
    sk += bfu(k16[base + (size_t)r * HD_]);
  }
  float qm = sq * (1.f / 82.f), km = sk * (1.f / 82.f);
  size_t oidx = ((size_t)h * MLM + im) * HD_ + d;
  ql[oidx] = qm;  qlh[oidx] = f2bf(qm);
  kl[oidx] = km;  klh[oidx] = f2bf(km);
}

// ---------------- a2 = softmax(ql @ kl^T) ----------------
__global__ __launch_bounds__(256) void a2_kernel(
    const float* __restrict__ ql, const float* __restrict__ kl,
    float* __restrict__ a2){
  const int im = blockIdx.x, h = blockIdx.y, t = threadIdx.x;
  __shared__ __align__(16) float qs[64];
  __shared__ float s4[4];
  if (t < 64) qs[t] = ql[((size_t)h * MLM + im) * HD_ + t];
  __syncthreads();
  const float4* kr4 = (const float4*)(kl + ((size_t)h * MLM + t) * HD_);
  const float4* qs4 = (const float4*)qs;
  float s = 0.f;
#pragma unroll
  for (int d4 = 0; d4 < 16; d4++){
    float4 kv = kr4[d4], qv = qs4[d4];
    s += qv.x*kv.x + qv.y*kv.y + qv.z*kv.z + qv.w*kv.w;
  }
  float mx = blockMax256(s, s4);
  float e = __expf(s - mx);
  float S = blockSum256(e, s4);
  a2[((size_t)h * MLM + im) * MLM + t] = e / S;
}

// ---------------- pinv scale: per-head slots, no atomics ----------------
// grid 8, block 256
__global__ __launch_bounds__(256) void pinv_scale_kernel(
    const float* __restrict__ a2, float* __restrict__ scal){
  const int h = blockIdx.x, j = threadIdx.x;
  const float* A = a2 + (size_t)h * MLM * MLM;
  float rs = 0.f, cs = 0.f;
  for (int t = 0; t < MLM; t++){
    rs += fabsf(A[(size_t)j * MLM + t]);
    cs += fabsf(A[(size_t)t * MLM + j]);
  }
  __shared__ float s4[4];
  float rmax = blockMax256(rs, s4);
  float cmax = blockMax256(cs, s4);
  if (j == 0){ scal[h * 2] = rmax; scal[h * 2 + 1] = cmax; }
}

// grid (256, 8), block 256: z = a2^T / (max rmax * max cmax)
__global__ __launch_bounds__(256) void pinv_init_kernel(
    const float* __restrict__ a2, const float* __restrict__ scal,
    float* __restrict__ z){
  const int i = blockIdx.x, h = blockIdx.y, j = threadIdx.x;
  float rmax = scal[0], cmax = scal[1];
#pragma unroll
  for (int hh = 1; hh < 8; hh++){
    rmax = fmaxf(rmax, scal[hh * 2]);
    cmax = fmaxf(cmax, scal[hh * 2 + 1]);
  }
  float inv = 1.f / (rmax * cmax);
  z[((size_t)h * MLM + i) * MLM + j] = a2[((size_t)h * MLM + j) * MLM + i] * inv;
}

// ---------------- batched 256^3: C = c1*(A @ (c0*I + sgn*B)), split-bf16 MFMA --
// hi/lo two-term split: A*B ~= Ah*Bh + Ah*Bl + Al*Bh (error ~2^-16 rel).
// grid (4,4,8), block 256 (4 waves).
__global__ __launch_bounds__(256) void bmm256_mfma_kernel(
    const float* __restrict__ Ab, const float* __restrict__ Bb,
    float* __restrict__ Cb, float c0, float sgn, float c1){
  __shared__ unsigned short Ash[64 * 40], Asl[64 * 40];
  __shared__ unsigned short Bsh[64 * 40], Bsl[64 * 40];
  const int h = blockIdx.z;
  const float* A = Ab + (size_t)h * 65536;
  const float* B = Bb + (size_t)h * 65536;
  float* C = Cb + (size_t)h * 65536;
  const int bm = blockIdx.x * 64, bn = blockIdx.y * 64;
  const int t = threadIdx.x, lane = t & 63, w = t >> 6;
  const int wr = w >> 1, wc = w & 1, m16 = lane & 15, quad = lane >> 4;
  f32x4 z4 = {0.f, 0.f, 0.f, 0.f};
  f32x4 acc[2][2] = {{z4, z4}, {z4, z4}};
  for (int kc = 0; kc < 256; kc += 32){
    {
      int row = t >> 2, c8 = (t & 3) * 8;
      const float* src = A + (size_t)(bm + row) * 256 + kc + c8;
      float xs[8];
      *(float4*)(xs)     = *(const float4*)src;
      *(float4*)(xs + 4) = *(const float4*)(src + 4);
#pragma unroll
      for (int j = 0; j < 8; j++){
        unsigned short hi = f2bf(xs[j]);
        Ash[row * 40 + c8 + j] = hi;
        Asl[row * 40 + c8 + j] = f2bf(xs[j] - bfu(hi));
      }
      int k = t >> 3, n8 = (t & 7) * 8;
      const float* bsrc = B + (size_t)(kc + k) * 256 + bn + n8;
      float ys[8];
      *(float4*)(ys)     = *(const float4*)bsrc;
      *(float4*)(ys + 4) = *(const float4*)(bsrc + 4);
#pragma unroll
      for (int j = 0; j < 8; j++){
        float xv = sgn * ys[j];
        if (kc + k == bn + n8 + j) xv += c0;
        unsigned short hi = f2bf(xv);
        Bsh[(n8 + j) * 40 + k] = hi;
        Bsl[(n8 + j) * 40 + k] = f2bf(xv - bfu(hi));
      }
    }
    __syncthreads();
    bf16x8 ah[2], al[2], bh[2], bl[2];
#pragma unroll
    for (int mi = 0; mi < 2; mi++){
      ah[mi] = *(const bf16x8*)(Ash + (wr * 32 + mi * 16 + m16) * 40 + quad * 8);
      al[mi] = *(const bf16x8*)(Asl + (wr * 32 + mi * 16 + m16) * 40 + quad * 8);
      bh[mi] = *(const bf16x8*)(Bsh + (wc * 32 + mi * 16 + m16) * 40 + quad * 8);
      bl[mi] = *(const bf16x8*)(Bsl + (wc * 32 + mi * 16 + m16) * 40 + quad * 8);
    }
#pragma unroll
    for (int mi = 0; mi < 2; mi++)
#pragma unroll
      for (int ni = 0; ni < 2; ni++){
        acc[mi][ni] = __builtin_amdgcn_mfma_f32_16x16x32_bf16(ah[mi], bh[ni], acc[mi][ni], 0, 0, 0);
        acc[mi][ni] = __builtin_amdgcn_mfma_f32_16x16x32_bf16(ah[mi], bl[ni], acc[mi][ni], 0, 0, 0);
        acc[mi][ni] = __builtin_amdgcn_mfma_f32_16x16x32_bf16(al[mi], bh[ni], acc[mi][ni], 0, 0, 0);
      }
    __syncthreads();
  }
#pragma unroll
  for (int mi = 0; mi < 2; mi++)
#pragma unroll
    for (int ni = 0; ni < 2; ni++)
#pragma unroll
      for (int r = 0; r < 4; r++){
        int row = bm + wr * 32 + mi * 16 + quad * 4 + r;
        int col = bn + wc * 32 + ni * 16 + m16;
        C[(size_t)row * 256 + col] = c1 * acc[mi][ni][r];
      }
}

// ---------------- a3v split-K flash, bf16 MFMA ----------------
__global__ __launch_bounds__(256) void a3v_part_kernel(
    const unsigned short* __restrict__ qlh, const unsigned short* __restrict__ k16,
    const unsigned short* __restrict__ v16, float* __restrict__ pacc,
    float* __restrict__ pml){
  __shared__ __align__(16) unsigned short qs16[64 * 72];
  __shared__ __align__(16) unsigned short kb16[64 * 72];   // K, then P
  __shared__ __align__(16) unsigned short vt16[64 * 72];   // V^T [d][n]
  const int lt = blockIdx.x, h = blockIdx.y, ch = blockIdx.z;
  const int t = threadIdx.x;
  const int lane = t & 63, w = t >> 6;
  const int m16 = lane & 15, quad = lane >> 4;

  const unsigned short* qg = qlh + ((size_t)h * MLM + lt * 64) * HD_;
  for (int idx = t; idx < 512; idx += 256){
    int row = idx >> 3, off = (idx & 7) * 8;
    *(uint4*)(qs16 + row * 72 + off) = *(const uint4*)(qg + (size_t)row * HD_ + off);
  }
  f32x4 z4 = {0.f, 0.f, 0.f, 0.f};
  f32x4 acc_o[4] = {z4, z4, z4, z4};
  float mreg[4], lreg[4];
#pragma unroll
  for (int r = 0; r < 4; r++){ mreg[r] = -3.0e38f; lreg[r] = 0.f; }
  const unsigned short* kg = k16 + ((size_t)h * NP_ + ch * CHTOK) * HD_;
  const unsigned short* vg = v16 + ((size_t)h * NP_ + ch * CHTOK) * HD_;

  for (int sc = 0; sc < 8; sc++){
    __syncthreads();
    for (int idx = t; idx < 512; idx += 256){
      int row = idx >> 3, off = (idx & 7) * 8;
      *(uint4*)(kb16 + row * 72 + off) =
          *(const uint4*)(kg + (size_t)(sc * 64 + row) * HD_ + off);
      uint4 pv = *(const uint4*)(vg + (size_t)(sc * 64 + row) * HD_ + off);
      unsigned int uu[4] = {pv.x, pv.y, pv.z, pv.w};
#pragma unroll
      for (int j = 0; j < 4; j++){
        vt16[(off + 2 * j)     * 72 + row] = (unsigned short)(uu[j] & 0xffffu);
        vt16[(off + 2 * j + 1) * 72 + row] = (unsigned short)(uu[j] >> 16);
      }
    }
    __syncthreads();
    f32x4 acc_s[4] = {z4, z4, z4, z4};
#pragma unroll
    for (int kc = 0; kc < 64; kc += 32){
      bf16x8 a = *(const bf16x8*)(qs16 + (w * 16 + m16) * 72 + kc + quad * 8);
#pragma unroll
      for (int ni = 0; ni < 4; ni++){
        bf16x8 b = *(const bf16x8*)(kb16 + (ni * 16 + m16) * 72 + kc + quad * 8);
        acc_s[ni] = __builtin_amdgcn_mfma_f32_16x16x32_bf16(a, b, acc_s[ni], 0, 0, 0);
      }
    }
    __syncthreads();
#pragma unroll
    for (int r = 0; r < 4; r++){
      float cm = fmaxf(fmaxf(acc_s[0][r], acc_s[1][r]), fmaxf(acc_s[2][r], acc_s[3][r]));
#pragma unroll
      for (int o = 1; o < 16; o <<= 1) cm = fmaxf(cm, __shfl_xor(cm, o));
      float mn = fmaxf(mreg[r], cm);
      float scl = __expf(mreg[r] - mn);
      float p0 = __expf(acc_s[0][r] - mn), p1 = __expf(acc_s[1][r] - mn);
      float p2 = __expf(acc_s[2][r] - mn), p3 = __expf(acc_s[3][r] - mn);
      float ls = (p0 + p1) + (p2 + p3);
#pragma unroll
      for (int o = 1; o < 16; o <<= 1) ls += __shfl_xor(ls, o);
      lreg[r] = lreg[r] * scl + ls;
      mreg[r] = mn;
      acc_o[0][r] *= scl; acc_o[1][r] *= scl;
      acc_o[2][r] *= scl; acc_o[3][r] *= scl;
      int prow = (w * 16 + quad * 4 + r) * 72 + m16;
      kb16[prow + 0]  = f2bf(p0);
      kb16[prow + 16] = f2bf(p1);
      kb16[prow + 32] = f2bf(p2);
      kb16[prow + 48] = f2bf(p3);
    }
    __syncthreads();
#pragma unroll
    for (int kc = 0; kc < 64; kc += 32){
      bf16x8 a = *(const bf16x8*)(kb16 + (w * 16 + m16) * 72 + kc + quad * 8);
#pragma unroll
      for (int ni = 0; ni < 4; ni++){
        bf16x8 b = *(const bf16x8*)(vt16 + (ni * 16 + m16) * 72 + kc + quad * 8);
        acc_o[ni] = __builtin_amdgcn_mfma_f32_16x16x32_bf16(a, b, acc_o[ni], 0, 0, 0);
      }
    }
  }
#pragma unroll
  for (int r = 0; r < 4; r++){
    int im = lt * 64 + w * 16 + quad * 4 + r;
    size_t base = ((size_t)h * NCH + ch) * MLM + im;
#pragma unroll
    for (int ni = 0; ni < 4; ni++)
      pacc[base * HD_ + ni * 16 + m16] = acc_o[ni][r];
    if (m16 == 0){
      pml[base * 2]     = mreg[r];
      pml[base * 2 + 1] = lreg[r];
    }
  }
}

__global__ __launch_bounds__(64) void a3v_combine_kernel(
    const float* __restrict__ pacc, const float* __restrict__ pml,
    float* __restrict__ t1){
  const int im = blockIdx.x, h = blockIdx.y, lane = threadIdx.x;
  float M = -3.0e38f;
  for (int c = 0; c < NCH; c++)
    M = fmaxf(M, pml[(((size_t)h * NCH + c) * MLM + im) * 2]);
  float accv = 0.f, L = 0.f;
  for (int c = 0; c < NCH; c++){
    size_t base = ((size_t)h * NCH + c) * MLM + im;
    float mc = pml[base * 2], lc = pml[base * 2 + 1];
    float w = __expf(mc - M);
    accv += w * pacc[base * HD_ + lane];
    L += w * lc;
  }
  t1[((size_t)h * MLM + im) * HD_ + lane] = accv / L;
}

// ---------------- t2^T = (z @ t1)^T, bf16 [h][d][im] ----------------
__global__ __launch_bounds__(256) void zt1_kernel(
    const float* __restrict__ z, const float* __restrict__ t1,
    unsigned short* __restrict__ t2t){
  const int h = blockIdx.y;
  const int t = threadIdx.x;
  const int d = t & 63, ri = t >> 6;
  const int im = blockIdx.x * 4 + ri;
  const float* zr = z + ((size_t)h * MLM + im) * MLM;
  const float* t1h = t1 + (size_t)h * MLM * HD_;
  float acc = 0.f;
#pragma unroll 8
  for (int kk = 0; kk < MLM; kk++) acc += zr[kk] * t1h[(size_t)kk * HD_ + d];
  t2t[((size_t)h * HD_ + d) * MLM + im] = f2bf(acc);
}

// ---------------- out tile MFMA: 64 tokens x 1 head per block ----------------
__global__ __launch_bounds__(256) void out_tile_kernel(
    const unsigned short* __restrict__ q16, const unsigned short* __restrict__ klh,
    const unsigned short* __restrict__ t2t, const unsigned short* __restrict__ v16,
    const float* __restrict__ resw, unsigned short* __restrict__ outh){
  __shared__ __align__(16) unsigned short smem[64 * 72 * 2 + 64 * 264];
  unsigned short* qs16 = smem;                 // 64 x 72
  unsigned short* kb16 = smem + 64 * 72;       // 64 x 72 (kl chunks, t2t chunks)
  unsigned short* Ps   = smem + 64 * 72 * 2;   // 64 x 264 (P bf16; later O f32 + v tile)
  const int tile = blockIdx.x, h = blockIdx.y;
  const int n0 = PADR + tile * 64;
  const int t = threadIdx.x;
  const int lane = t & 63, w = t >> 6;
  const int m16 = lane & 15, quad = lane >> 4;

  {
    const unsigned short* qh = q16 + (size_t)h * NP_ * HD_;
    for (int idx = t; idx < 512; idx += 256){
      int row = idx >> 3, off = (idx & 7) * 8;
      int n = n0 + row;
      uint4 val = {0u, 0u, 0u, 0u};
      if (n < NP_) val = *(const uint4*)(qh + (size_t)n * HD_ + off);
      *(uint4*)(qs16 + row * 72 + off) = val;
    }
  }
  f32x4 z4 = {0.f, 0.f, 0.f, 0.f};
  f32x4 acc_s[16];
#pragma unroll
  for (int i = 0; i < 16; i++) acc_s[i] = z4;
  const unsigned short* klg = klh + (size_t)h * MLM * HD_;
  for (int m = 0; m < 4; m++){
    __syncthreads();
    for (int idx = t; idx < 512; idx += 256){
      int row = idx >> 3, off = (idx & 7) * 8;
      *(uint4*)(kb16 + row * 72 + off) =
          *(const uint4*)(klg + (size_t)(m * 64 + row) * HD_ + off);
    }
    __syncthreads();
#pragma unroll
    for (int kc = 0; kc < 64; kc += 32){
      bf16x8 a = *(const bf16x8*)(qs16 + (w * 16 + m16) * 72 + kc + quad * 8);
#pragma unroll
      for (int ni = 0; ni < 4; ni++){
        bf16x8 b = *(const bf16x8*)(kb16 + (ni * 16 + m16) * 72 + kc + quad * 8);
        acc_s[m * 4 + ni] = __builtin_amdgcn_mfma_f32_16x16x32_bf16(a, b, acc_s[m * 4 + ni], 0, 0, 0);
      }
    }
  }
  __syncthreads();
#pragma unroll
  for (int r = 0; r < 4; r++){
    float mx = acc_s[0][r];
#pragma unroll
    for (int mc = 1; mc < 16; mc++) mx = fmaxf(mx, acc_s[mc][r]);
#pragma unroll
    for (int o = 1; o < 16; o <<= 1) mx = fmaxf(mx, __shfl_xor(mx, o));
    float p[16]; float sum = 0.f;
#pragma unroll
    for (int mc = 0; mc < 16; mc++){ p[mc] = __expf(acc_s[mc][r] - mx); sum += p[mc]; }
#pragma unroll
    for (int o = 1; o < 16; o <<= 1) sum += __shfl_xor(sum, o);
    float inv = 1.f / sum;
    int prow = (w * 16 + quad * 4 + r) * 264;
#pragma unroll
    for (int mc = 0; mc < 16; mc++)
      Ps[prow + (mc >> 2) * 64 + (mc & 3) * 16 + m16] = f2bf(p[mc] * inv);
  }
  f32x4 acc_o[4] = {z4, z4, z4, z4};
  const unsigned short* t2g = t2t + (size_t)h * HD_ * MLM;
  for (int ch = 0; ch < 4; ch++){
    __syncthreads();
    {
      int row = t >> 2, c8 = (t & 3) * 16;
      const unsigned short* src = t2g + (size_t)row * MLM + ch * 64 + c8;
      *(uint4*)(kb16 + row * 72 + c8)     = *(const uint4*)src;
      *(uint4*)(kb16 + row * 72 + c8 + 8) = *(const uint4*)(src + 8);
    }
    __syncthreads();
#pragma unroll
    for (int kc = 0; kc < 64; kc += 32){
      bf16x8 a = *(const bf16x8*)(Ps + (w * 16 + m16) * 264 + ch * 64 + kc + quad * 8);
#pragma unroll
      for (int ni = 0; ni < 4; ni++){
        bf16x8 b = *(const bf16x8*)(kb16 + (ni * 16 + m16) * 72 + kc + quad * 8);
        acc_o[ni] = __builtin_amdgcn_mfma_f32_16x16x32_bf16(a, b, acc_o[ni], 0, 0, 0);
      }
    }
  }
  __syncthreads();
  float* Obuf = (float*)Ps;                          // 64 x 66 f32
  unsigned short* vtile = (unsigned short*)(Obuf + 64 * 66);  // 96 x 72 bf16
#pragma unroll
  for (int r = 0; r < 4; r++){
    int row = w * 16 + quad * 4 + r;
#pragma unroll
    for (int ni = 0; ni < 4; ni++)
      Obuf[row * 66 + ni * 16 + m16] = acc_o[ni][r];
  }
  {
    const unsigned short* vh = v16 + (size_t)h * NP_ * HD_;
    for (int idx = t; idx < 768; idx += 256){
      int row = idx >> 3, off = (idx & 7) * 8;
      int nn = n0 - 16 + row;
      uint4 val = {0u, 0u, 0u, 0u};
      if (nn < NP_) val = *(const uint4*)(vh + (size_t)nn * HD_ + off);
      *(uint4*)(vtile + row * 72 + off) = val;
    }
  }
  __syncthreads();
  float wreg[33];
  {
    const float* wr = resw + h * 33;
#pragma unroll
    for (int kk = 0; kk < 33; kk++) wreg[kk] = wr[kk];
  }
  const int ty = t >> 4, tx = t & 15;
#pragma unroll
  for (int i = 0; i < 4; i++){
    int lrow = ty * 4 + i;
    float c0v = 0.f, c1v = 0.f, c2v = 0.f, c3v = 0.f;
    for (int kk = 0; kk < 33; kk++){
      uint2 uv = *(const uint2*)(vtile + (lrow + kk) * 72 + tx * 4);
      float wv = wreg[kk];
      c0v += __uint_as_float(uv.x << 16) * wv;
      c1v += __uint_as_float(uv.x & 0xffff0000u) * wv;
      c2v += __uint_as_float(uv.y << 16) * wv;
      c3v += __uint_as_float(uv.y & 0xffff0000u) * wv;
    }
    int trow = tile * 64 + lrow;
    if (trow < NTOK){
      const float* orow = Obuf + lrow * 66 + tx * 4;
      unsigned long long pk =
          (unsigned long long)f2bf(orow[0] + c0v)
        | ((unsigned long long)f2bf(orow[1] + c1v) << 16)
        | ((unsigned long long)f2bf(orow[2] + c2v) << 32)
        | ((unsigned long long)f2bf(orow[3] + c3v) << 48);
      *(unsigned long long*)(outh + (size_t)trow * D_ + h * HD_ + tx * 4) = pk;
    }
  }
}

// ---------------- proj MFMA: h += outh @ out_wt^T + bias ----------------
__global__ __launch_bounds__(256) void proj_mfma_kernel(
    const unsigned short* __restrict__ A, const unsigned short* __restrict__ Bt,
    const float* __restrict__ bias, float* __restrict__ h){
  __shared__ unsigned short As[64 * 72], Bs[64 * 72];
  f32x4 z4 = {0.f, 0.f, 0.f, 0.f};
  f32x4 acc[2][2] = {{z4, z4}, {z4, z4}};
  const int bm = blockIdx.x * 64, bn = blockIdx.y * 64;
  mfma_tile64(A, NTOK, bm, Bt, bn, D_, acc, As, Bs);
  const int lane = threadIdx.x & 63, wave = threadIdx.x >> 6;
  const int wr = wave >> 1, wc = wave & 1;
  const int m16 = lane & 15, quad = lane >> 4;
#pragma unroll
  for (int mi = 0; mi < 2; mi++)
#pragma unroll
    for (int ni = 0; ni < 2; ni++){
      int col = bn + wc * 32 + ni * 16 + m16;
      float bv = bias[col];
#pragma unroll
      for (int r = 0; r < 4; r++){
        int row = bm + wr * 32 + mi * 16 + quad * 4 + r;
        if (row < NTOK) h[(size_t)row * D_ + col] += acc[mi][ni][r] + bv;
      }
    }
}

// ---------------- PPEG ----------------
__global__ __launch_bounds__(512) void ppeg_combine_kernel(
    const float* __restrict__ w7, const float* __restrict__ b7,
    const float* __restrict__ w5, const float* __restrict__ b5,
    const float* __restrict__ w3, const float* __restrict__ b3,
    float* __restrict__ wcomb, float* __restrict__ bcomb){
  const int c = threadIdx.x;
#pragma unroll
  for (int i = 0; i < 7; i++){
#pragma unroll
    for (int j = 0; j < 7; j++){
      int di = i - 3, dj = j - 3;
      float wv = w7[(size_t)c * 49 + i * 7 + j];
      if (di >= -2 && di <= 2 && dj >= -2 && dj <= 2)
        wv += w5[(size_t)c * 25 + (di + 2) * 5 + (dj + 2)];
      if (di >= -1 && di <= 1 && dj >= -1 && dj <= 1)
        wv += w3[(size_t)c * 9 + (di + 1) * 3 + (dj + 1)];
      if (di == 0 && dj == 0) wv += 1.f;
      wcomb[(size_t)(i * 7 + j) * 512 + c] = wv;
    }
  }
  bcomb[c] = b7[c] + b5[c] + b3[c];
}

__global__ __launch_bounds__(512) void ppeg_conv_kernel(
    const float* __restrict__ h, const float* __restrict__ wcomb,
    const float* __restrict__ bcomb, float* __restrict__ tmp){
  const int c = threadIdx.x;
  const int y = blockIdx.y;
  const int x0 = blockIdx.x * 8;
  float wc[49];
#pragma unroll
  for (int kk = 0; kk < 49; kk++) wc[kk] = wcomb[(size_t)kk * 512 + c];
  float acc[8];
  const float bv = bcomb[c];
#pragma unroll
  for (int p = 0; p < 8; p++) acc[p] = bv;
#pragma unroll
  for (int i = 0; i < 7; i++){
    const int yy = y + i - 3;
    if (yy < 0 || yy >= HHW) continue;
    const float* hrow = h + (size_t)(1 + yy * HHW) * D_ + c;
    float line[14];
#pragma unroll
    for (int j = 0; j < 14; j++){
      const int xx = x0 + j - 3;
      line[j] = (xx >= 0 && xx < HHW) ? hrow[(size_t)xx * D_] : 0.f;
    }
#pragma unroll
    for (int p = 0; p < 8; p++)
#pragma unroll
      for (int j = 0; j < 7; j++)
        acc[p] += line[p + j] * wc[i * 7 + j];
  }
#pragma unroll
  for (int p = 0; p < 8; p++)
    tmp[(size_t)(y * HHW + x0 + p) * D_ + c] = acc[p];
}

__global__ void ppeg_copy_kernel(const float* __restrict__ tmp, float* __restrict__ h){
  size_t idx = (size_t)blockIdx.x * 256 + threadIdx.x;
  if (idx < (size_t)NFEAT * D_) h[idx + D_] = tmp[idx];
}

// ---------------- final ----------------
__global__ __launch_bounds__(512) void final_kernel(
    const float* __restrict__ h, const float* __restrict__ w,
    const float* __restrict__ b, const float* __restrict__ fc3w,
    const float* __restrict__ fc3b, float* __restrict__ out){
  __shared__ float vec[512];
  __shared__ float s8[8];
  __shared__ float lg[4];
  const int t = threadIdx.x;
  float x = h[t];
  float v = waveSumF(x);
  if ((t & 63) == 0) s8[t >> 6] = v;
  __syncthreads();
  float sum = 0.f;
#pragma unroll
  for (int i = 0; i < 8; i++) sum += s8[i];
  float mu = sum * (1.f / 512.f);
  __syncthreads();
  float d = x - mu;
  v = waveSumF(d * d);
  if ((t & 63) == 0) s8[t >> 6] = v;
  __syncthreads();
  float var = 0.f;
#pragma unroll
  for (int i = 0; i < 8; i++) var += s8[i];
  var *= (1.f / 512.f);
  float rs = rsqrtf(var + 1e-5f);
  vec[t] = d * rs * w[t] + b[t];
  __syncthreads();
  if (t < 4){
    float acc = fc3b[t];
    for (int kk = 0; kk < 512; kk++) acc += vec[kk] * fc3w[kk * 4 + t];
    lg[t] = acc;
  }
  __syncthreads();
  if (t == 0){
    float m = fmaxf(fmaxf(lg[0], lg[1]), fmaxf(lg[2], lg[3]));
    float e[4], se = 0.f;
#pragma unroll
    for (int i = 0; i < 4; i++){ e[i] = __expf(lg[i] - m); se += e[i]; }
    int am = 0; float bm = lg[0];
#pragma unroll
    for (int i = 1; i < 4; i++) if (lg[i] > bm){ bm = lg[i]; am = i; }
#pragma unroll
    for (int i = 0; i < 4; i++){ out[i] = lg[i]; out[4 + i] = e[i] / se; }
    out[8] = (float)am;
  }
}

// ---------------------------------------------------------------------------
extern "C" void kernel_launch(void* const* d_in, const int* in_sizes, int n_in,
                              void* d_out, int out_size, void* d_ws, size_t ws_size,
                              hipStream_t stream) {
  const float* x       = (const float*)d_in[0];
  const float* fc1_w   = (const float*)d_in[1];
  const float* fc1_b   = (const float*)d_in[2];
  const float* cls_tok = (const float*)d_in[3];
  const float* l1_nw   = (const float*)d_in[4];
  const float* l1_nb   = (const float*)d_in[5];
  const float* l1_qkvw = (const float*)d_in[6];
  const float* l1_outw = (const float*)d_in[7];
  const float* l1_outb = (const float*)d_in[8];
  const float* l1_resw = (const float*)d_in[9];
  const float* ppeg_w7 = (const float*)d_in[10];
  const float* ppeg_b7 = (const float*)d_in[11];
  const float* ppeg_w5 = (const float*)d_in[12];
  const float* ppeg_b5 = (const float*)d_in[13];
  const float* ppeg_w3 = (const float*)d_in[14];
  const float* ppeg_b3 = (const float*)d_in[15];
  const float* l2_nw   = (const float*)d_in[16];
  const float* l2_nb   = (const float*)d_in[17];
  const float* l2_qkvw = (const float*)d_in[18];
  const float* l2_outw = (const float*)d_in[19];
  const float* l2_outb = (const float*)d_in[20];
  const float* l2_resw = (const float*)d_in[21];
  const float* norm_w  = (const float*)d_in[22];
  const float* norm_b  = (const float*)d_in[23];
  const float* fc3_w   = (const float*)d_in[24];
  const float* fc3_b   = (const float*)d_in[25];

  // workspace layout (float units)
  float* W = (float*)d_ws;
  size_t o = 0;
  float* hbuf = W + o; o += (size_t)NTOK * D_;
  float* xp   = W + o; o += (size_t)NP_ * D_;   // xph / pacc+pml / outh / ppeg tmp
  float* qb   = W + o; o += (size_t)NH_ * NP_ * HD_;   // bf16 q; also Ah pre-layer
  float* kb   = W + o; o += (size_t)NH_ * NP_ * HD_;   // bf16 k
  float* vb   = W + o; o += (size_t)NH_ * NP_ * HD_;   // bf16 v
  float* qlb  = W + o; o += (size_t)NH_ * MLM * HD_;
  float* klb  = W + o; o += (size_t)NH_ * MLM * HD_;
  float* a2b  = W + o; o += (size_t)NH_ * MLM * MLM;
  float* z0   = W + o; o += (size_t)NH_ * MLM * MLM;
  float* z1   = W + o; o += (size_t)NH_ * MLM * MLM;
  float* ta   = W + o; o += (size_t)NH_ * MLM * MLM;
  float* tb   = W + o; o += (size_t)NH_ * MLM * MLM;
  float* tc   = W + o; o += (size_t)NH_ * MLM * MLM;
  float* t1b  = W + o; o += (size_t)NH_ * MLM * HD_;
  float* t2r  = W + o; o += (size_t)NH_ * MLM * HD_;   // t2t bf16 lives here
  float* scalf = W + o; o += 16;
  float* wcomb = W + o; o += 49 * 512;
  float* bcomb = W + o; o += 512;
  unsigned short* fc1_wt  = (unsigned short*)(W + o); o += (size_t)D_ * E_ / 2;
  unsigned short* qkv_wt1 = (unsigned short*)(W + o); o += (size_t)1536 * D_ / 2;
  unsigned short* qkv_wt2 = (unsigned short*)(W + o); o += (size_t)1536 * D_ / 2;
  unsigned short* out_wt1 = (unsigned short*)(W + o); o += (size_t)D_ * D_ / 2;
  unsigned short* out_wt2 = (unsigned short*)(W + o); o += (size_t)D_ * D_ / 2;
  unsigned short* qlh = (unsigned short*)(W + o); o += (size_t)NH_ * MLM * HD_ / 2;
  unsigned short* klh = (unsigned short*)(W + o); o += (size_t)NH_ * MLM * HD_ / 2;

  unsigned short* xph = (unsigned short*)xp;
  float* pacc = xp;
  float* pml  = xp + (size_t)NH_ * NCH * MLM * HD_;
  unsigned short* outh = (unsigned short*)xp;
  unsigned short* Ah  = (unsigned short*)qb;
  unsigned short* q16 = (unsigned short*)qb;
  unsigned short* k16 = (unsigned short*)kb;
  unsigned short* v16 = (unsigned short*)vb;
  unsigned short* t2t = (unsigned short*)t2r;

  // ---- weight prep (once per launch) ----
  wtrans_kernel<<<dim3(E_ / 32, D_ / 32), dim3(32, 8), 0, stream>>>(fc1_w, fc1_wt, E_, D_);
  wtrans_kernel<<<dim3(D_ / 32, 1536 / 32), dim3(32, 8), 0, stream>>>(l1_qkvw, qkv_wt1, D_, 1536);
  wtrans_kernel<<<dim3(D_ / 32, 1536 / 32), dim3(32, 8), 0, stream>>>(l2_qkvw, qkv_wt2, D_, 1536);
  wtrans_kernel<<<dim3(D_ / 32, D_ / 32), dim3(32, 8), 0, stream>>>(l1_outw, out_wt1, D_, D_);
  wtrans_kernel<<<dim3(D_ / 32, D_ / 32), dim3(32, 8), 0, stream>>>(l2_outw, out_wt2, D_, D_);
  ppeg_combine_kernel<<<1, 512, 0, stream>>>(ppeg_w7, ppeg_b7, ppeg_w5, ppeg_b5,
                                             ppeg_w3, ppeg_b3, wcomb, bcomb);

  // ---- fc1 (maxpool -> bf16 -> MFMA) ----
  pool_bf16_kernel<<<20480, 256, 0, stream>>>(x, Ah);
  fc1_mfma_kernel<<<dim3(320, 8), 256, 0, stream>>>(Ah, fc1_wt, fc1_b, hbuf);
  cls_kernel<<<2, 256, 0, stream>>>(cls_tok, hbuf);

  auto run_layer = [&](const float* nw, const float* nb,
                       const unsigned short* qkvwt, const unsigned short* outwt,
                       const float* outb, const float* resw){
    ln_pad_kernel<<<NP_, 256, 0, stream>>>(hbuf, nw, nb, xph);
    qkv_mfma_kernel<<<dim3(328, 24), 256, 0, stream>>>(xph, qkvwt, q16, k16, v16);
    landmark_kernel<<<dim3(256, 8), 64, 0, stream>>>(q16, k16, qlb, klb, qlh, klh);
    a2_kernel<<<dim3(256, 8), 256, 0, stream>>>(qlb, klb, a2b);
    pinv_scale_kernel<<<8, 256, 0, stream>>>(a2b, scalf);
    pinv_init_kernel<<<dim3(256, 8), 256, 0, stream>>>(a2b, scalf, z0);
    float* zc = z0; float* za = z1;
    for (int it = 0; it < 6; it++){
      bmm256_mfma_kernel<<<dim3(4, 4, 8), 256, 0, stream>>>(a2b, zc, ta, 0.f, 1.f, 1.f);
      bmm256_mfma_kernel<<<dim3(4, 4, 8), 256, 0, stream>>>(ta, ta, tb, 7.f, -1.f, 1.f);
      bmm256_mfma_kernel<<<dim3(4, 4, 8), 256, 0, stream>>>(ta, tb, tc, 15.f, -1.f, 1.f);
      bmm256_mfma_kernel<<<dim3(4, 4, 8), 256, 0, stream>>>(zc, tc, za, 13.f, -1.f, 0.25f);
      float* tswap = zc; zc = za; za = tswap;
    }
    a3v_part_kernel<<<dim3(4, 8, NCH), 256, 0, stream>>>(qlh, k16, v16, pacc, pml);
    a3v_combine_kernel<<<dim3(256, 8), 64, 0, stream>>>(pacc, pml, t1b);
    zt1_kernel<<<dim3(64, 8), 256, 0, stream>>>(zc, t1b, t2t);
    out_tile_kernel<<<dim3(325, 8), 256, 0, stream>>>(q16, klh, t2t, v16, resw, outh);
    proj_mfma_kernel<<<dim3(325, 8), 256, 0, stream>>>(outh, outwt, outb, hbuf);
  };

  run_layer(l1_nw, l1_nb, qkv_wt1, out_wt1, l1_outb, l1_resw);
  ppeg_conv_kernel<<<dim3(HHW / 8, HHW), 512, 0, stream>>>(hbuf, wcomb, bcomb, xp);
  ppeg_copy_kernel<<<(NFEAT * D_ + 255) / 256, 256, 0, stream>>>(xp, hbuf);
  run_layer(l2_nw, l2_nb, qkv_wt2, out_wt2, l2_outb, l2_resw);
  final_kernel<<<1, 512, 0, stream>>>(hbuf, norm_w, norm_b, fc3_w, fc3_b, (float*)d_out);
}

// Round 10
// 1699.656 us; speedup vs baseline: 1.4706x; 1.0018x over previous
//
#include <hip/hip_runtime.h>

// ---------------------------------------------------------------------------
// TransMIL forward on MI355X.
//   r0: 12995 us baseline (all-fp32, classic 64x64 tiled GEMMs).
//   r1: 10182 us — PPEG collapsed to one combined 7x7 depthwise conv.
//   r2:  8278 us — out_kernel rewritten as fused 32-token tile kernel.
//   r3:  5546 us — a3v rewritten as split-K flash attention.
//   r4:  3723 us — fc1/qkv/proj GEMMs -> bf16 MFMA (16x16x32).
//   r5:  3025 us — a3v_part -> bf16 MFMA flash.
//   r6:  1735 us — out_tile -> bf16 MFMA; bmm256 -> split-bf16 MFMA.
//   r7/r8: 2500 us — REGRESSION: cooperative pinv (grid.sync ~25us each).
//   r9:  1703 us — discrete pinv restored; GEMM BK=64 kept (+30 us net —
//        lesson: 64-tile GEMMs were NOT barrier-bound).
//   r10: GEMM tile 64x64 -> 128x128 (4x MFMA per staged LDS byte; m93-ladder
//        says 343->517+ TF); PPEG ping-pong into h2 (copy kernel dropped).
// ---------------------------------------------------------------------------

constexpr int D_    = 512;
constexpr int E_    = 1024;
constexpr int NTOK  = 20737;
constexpr int NP_   = 20992;   // padded seq len (255 zero rows at FRONT)
constexpr int NH_   = 8;
constexpr int HD_   = 64;
constexpr int MLM   = 256;     // landmarks
constexpr int LCH   = 82;      // tokens per landmark
constexpr int HHW   = 144;
constexpr int NFEAT = 20736;   // 144*144
constexpr int PADR  = 255;
constexpr int NCH   = 41;      // a3v N-chunks
constexpr int CHTOK = 512;     // tokens per chunk (8 subchunks of 64)

typedef __attribute__((ext_vector_type(8))) short bf16x8;
typedef __attribute__((ext_vector_type(4))) float f32x4;

__device__ __forceinline__ unsigned short f2bf(float f){
  unsigned int u = __float_as_uint(f);
  unsigned int r = u + 0x7fffu + ((u >> 16) & 1u);
  return (unsigned short)(r >> 16);
}
__device__ __forceinline__ float bfu(unsigned short u){
  return __uint_as_float((unsigned int)u << 16);
}

// ---------------- reduction helpers ----------------
__device__ __forceinline__ float waveMaxF(float v){
#pragma unroll
  for (int o = 32; o > 0; o >>= 1) v = fmaxf(v, __shfl_xor(v, o));
  return v;
}
__device__ __forceinline__ float waveSumF(float v){
#pragma unroll
  for (int o = 32; o > 0; o >>= 1) v += __shfl_xor(v, o);
  return v;
}
__device__ __forceinline__ float blockMax256(float v, float* sbuf){
  v = waveMaxF(v);
  if ((threadIdx.x & 63) == 0) sbuf[threadIdx.x >> 6] = v;
  __syncthreads();
  float r = fmaxf(fmaxf(sbuf[0], sbuf[1]), fmaxf(sbuf[2], sbuf[3]));
  __syncthreads();
  return r;
}
__device__ __forceinline__ float blockSum256(float v, float* sbuf){
  v = waveSumF(v);
  if ((threadIdx.x & 63) == 0) sbuf[threadIdx.x >> 6] = v;
  __syncthreads();
  float r = sbuf[0] + sbuf[1] + sbuf[2] + sbuf[3];
  __syncthreads();
  return r;
}

// ---------------- weight prep: W[K][N] fp32 -> Wt[N][K] bf16 ----------------
__global__ __launch_bounds__(256) void wtrans_kernel(
    const float* __restrict__ W, unsigned short* __restrict__ Wt, int K, int N){
  __shared__ float tile[32][33];
  const int kb = blockIdx.x * 32, nb = blockIdx.y * 32;
  const int tx = threadIdx.x, ty = threadIdx.y;
  for (int i = ty; i < 32; i += 8) tile[i][tx] = W[(size_t)(kb + i) * N + nb + tx];
  __syncthreads();
  for (int i = ty; i < 32; i += 8)
    Wt[(size_t)(nb + i) * K + kb + tx] = f2bf(tile[tx][i]);
}

// ---------------- maxpool2 + bf16 ----------------
__global__ __launch_bounds__(256) void pool_bf16_kernel(
    const float* __restrict__ x, unsigned short* __restrict__ Ah){
  size_t idx4 = ((size_t)blockIdx.x * 256 + threadIdx.x) * 4;
  size_t m = idx4 >> 10, e = idx4 & 1023;
  float4 a = *(const float4*)(x + (m * 2) * E_ + e);
  float4 b = *(const float4*)(x + (m * 2 + 1) * E_ + e);
  unsigned long long pk =
      (unsigned long long)f2bf(fmaxf(a.x, b.x))
    | ((unsigned long long)f2bf(fmaxf(a.y, b.y)) << 16)
    | ((unsigned long long)f2bf(fmaxf(a.z, b.z)) << 32)
    | ((unsigned long long)f2bf(fmaxf(a.w, b.w)) << 48);
  *(unsigned long long*)(Ah + idx4) = pk;
}

// ---------------- MFMA 128x128 tile core, BK=64 (bf16 in, fp32 acc) ----------
// 4 waves; wave w -> 64x64 quadrant (wr=w>>1, wc=w&1), acc[4][4] f32x4.
// As/Bs: 128 rows x 72 shorts. 32 MFMAs/wave per barrier pair.
__device__ __forceinline__ void mfma_tile128(
    const unsigned short* __restrict__ A, int arows, int bm,
    const unsigned short* __restrict__ Bt, int bn, int K,
    f32x4 acc[4][4], unsigned short* As, unsigned short* Bs){
  const int t = threadIdx.x;
  const int lane = t & 63, wave = t >> 6;
  const int wr = wave >> 1, wc = wave & 1;
  const int m16 = lane & 15, quad = lane >> 4;
  for (int kc = 0; kc < K; kc += 64){
    for (int idx = t; idx < 1024; idx += 256){
      int row = idx >> 3, off = (idx & 7) * 8;
      int ga = bm + row;
      ulonglong2 av = {0ull, 0ull};
      if (ga < arows) av = *(const ulonglong2*)(A + (size_t)ga * K + kc + off);
      *(ulonglong2*)(As + row * 72 + off) = av;
      ulonglong2 bv = *(const ulonglong2*)(Bt + (size_t)(bn + row) * K + kc + off);
      *(ulonglong2*)(Bs + row * 72 + off) = bv;
    }
    __syncthreads();
#pragma unroll
    for (int k2 = 0; k2 < 64; k2 += 32){
      bf16x8 af[4], bf[4];
#pragma unroll
      for (int mi = 0; mi < 4; mi++)
        af[mi] = *(const bf16x8*)(As + (wr * 64 + mi * 16 + m16) * 72 + k2 + quad * 8);
#pragma unroll
      for (int ni = 0; ni < 4; ni++)
        bf[ni] = *(const bf16x8*)(Bs + (wc * 64 + ni * 16 + m16) * 72 + k2 + quad * 8);
#pragma unroll
      for (int mi = 0; mi < 4; mi++)
#pragma unroll
        for (int ni = 0; ni < 4; ni++)
          acc[mi][ni] = __builtin_amdgcn_mfma_f32_16x16x32_bf16(af[mi], bf[ni], acc[mi][ni], 0, 0, 0);
    }
    __syncthreads();
  }
}

// ---------------- fc1: relu(Ah @ fc1_wt^T + b) -> h rows ----------------
// grid (160, 4)
__global__ __launch_bounds__(256) void fc1_mfma_kernel(
    const unsigned short* __restrict__ Ah, const unsigned short* __restrict__ Bt,
    const float* __restrict__ bias, float* __restrict__ h){
  __shared__ unsigned short As[128 * 72], Bs[128 * 72];
  f32x4 z4 = {0.f, 0.f, 0.f, 0.f};
  f32x4 acc[4][4];
#pragma unroll
  for (int i = 0; i < 4; i++)
#pragma unroll
    for (int j = 0; j < 4; j++) acc[i][j] = z4;
  const int bm = blockIdx.x * 128, bn = blockIdx.y * 128;
  mfma_tile128(Ah, 20480, bm, Bt, bn, E_, acc, As, Bs);
  const int lane = threadIdx.x & 63, wave = threadIdx.x >> 6;
  const int wr = wave >> 1, wc = wave & 1;
  const int m16 = lane & 15, quad = lane >> 4;
#pragma unroll
  for (int mi = 0; mi < 4; mi++)
#pragma unroll
    for (int ni = 0; ni < 4; ni++){
      int col = bn + wc * 64 + ni * 16 + m16;
      float bv = bias[col];
#pragma unroll
      for (int r = 0; r < 4; r++){
        int row = bm + wr * 64 + mi * 16 + quad * 4 + r;
        float vv = fmaxf(acc[mi][ni][r] + bv, 0.f);
        h[(size_t)(1 + row) * D_ + col] = vv;
        if (row < 256) h[(size_t)(20481 + row) * D_ + col] = vv;
      }
    }
}

__global__ void cls_kernel(const float* __restrict__ cls, float* __restrict__ h){
  int c = blockIdx.x * 256 + threadIdx.x;
  if (c < D_) h[c] = cls[c];
}

// copy row 0 (cls) from src h to dst h (ppeg ping-pong)
__global__ void row0_copy_kernel(const float* __restrict__ src, float* __restrict__ dst){
  int c = blockIdx.x * 256 + threadIdx.x;
  if (c < D_) dst[c] = src[c];
}

// ---------------- layernorm -> zero-padded bf16 xph ----------------
__global__ __launch_bounds__(256) void ln_pad_kernel(
    const float* __restrict__ h, const float* __restrict__ w,
    const float* __restrict__ b, unsigned short* __restrict__ xph){
  const int r = blockIdx.x;
  const int t = threadIdx.x;
  if (r < PADR){
    xph[(size_t)r * D_ + t] = 0;
    xph[(size_t)r * D_ + 256 + t] = 0;
    return;
  }
  __shared__ float s4[4];
  const float* x = h + (size_t)(r - PADR) * D_;
  float a0 = x[t], a1 = x[t + 256];
  float mu = blockSum256(a0 + a1, s4) * (1.f / 512.f);
  float d0 = a0 - mu, d1 = a1 - mu;
  float var = blockSum256(d0 * d0 + d1 * d1, s4) * (1.f / 512.f);
  float rs = rsqrtf(var + 1e-5f);
  xph[(size_t)r * D_ + t]       = f2bf(d0 * rs * w[t] + b[t]);
  xph[(size_t)r * D_ + 256 + t] = f2bf(d1 * rs * w[t + 256] + b[t + 256]);
}

// ---------------- qkv MFMA: q/k/v all bf16 head-major (q scaled 1/8) ----------
// grid (164, 12)
__global__ __launch_bounds__(256) void qkv_mfma_kernel(
    const unsigned short* __restrict__ A, const unsigned short* __restrict__ Bt,
    unsigned short* __restrict__ q16, unsigned short* __restrict__ k16,
    unsigned short* __restrict__ v16){
  __shared__ unsigned short As[128 * 72], Bs[128 * 72];
  f32x4 z4 = {0.f, 0.f, 0.f, 0.f};
  f32x4 acc[4][4];
#pragma unroll
  for (int i = 0; i < 4; i++)
#pragma unroll
    for (int j = 0; j < 4; j++) acc[i][j] = z4;
  const int bm = blockIdx.x * 128, bn = blockIdx.y * 128;
  mfma_tile128(A, NP_, bm, Bt, bn, D_, acc, As, Bs);
  const int lane = threadIdx.x & 63, wave = threadIdx.x >> 6;
  const int wr = wave >> 1, wc = wave & 1;
  const int m16 = lane & 15, quad = lane >> 4;
#pragma unroll
  for (int mi = 0; mi < 4; mi++)
#pragma unroll
    for (int ni = 0; ni < 4; ni++){
      int col = bn + wc * 64 + ni * 16 + m16;
      int which = col >> 9, hh = (col >> 6) & 7, d = col & 63;
      size_t cbase = (size_t)hh * NP_ * HD_ + d;
      unsigned short* dst;
      float sc = 1.f;
      if (which == 0){ dst = q16; sc = 0.125f; }
      else if (which == 1) dst = k16;
      else dst = v16;
#pragma unroll
      for (int r = 0; r < 4; r++){
        int row = bm + wr * 64 + mi * 16 + quad * 4 + r;
        dst[cbase + (size_t)row * HD_] = f2bf(acc[mi][ni][r] * sc);
      }
    }
}

// ---------------- landmarks ----------------
__global__ __launch_bounds__(64) void landmark_kernel(
    const unsigned short* __restrict__ q16, const unsigned short* __restrict__ k16,
    float* __restrict__ ql, float* __restrict__ kl,
    unsigned short* __restrict__ qlh, unsigned short* __restrict__ klh){
  const int im = blockIdx.x, h = blockIdx.y, d = threadIdx.x;
  size_t base = ((size_t)h * NP_ + (size_t)im * LCH) * HD_ + d;
  float sq = 0.f, sk = 0.f;
  for (int r = 0; r < LCH; r++){
    sq += bfu(q16[base + (size_t)r * HD_]);
    sk += bfu(k16[base + (size_t)r * HD_]);
  }
  float qm = sq * (1.f / 82.f), km = sk * (1.f / 82.f);
  size_t oidx = ((size_t)h * MLM + im) * HD_ + d;
  ql[oidx] = qm;  qlh[oidx] = f2bf(qm);
  kl[oidx] = km;  klh[oidx] = f2bf(km);
}

// ---------------- a2 = softmax(ql @ kl^T) ----------------
__global__ __launch_bounds__(256) void a2_kernel(
    const float* __restrict__ ql, const float* __restrict__ kl,
    float* __restrict__ a2){
  const int im = blockIdx.x, h = blockIdx.y, t = threadIdx.x;
  __shared__ __align__(16) float qs[64];
  __shared__ float s4[4];
  if (t < 64) qs[t] = ql[((size_t)h * MLM + im) * HD_ + t];
  __syncthreads();
  const float4* kr4 = (const float4*)(kl + ((size_t)h * MLM + t) * HD_);
  const float4* qs4 = (const float4*)qs;
  float s = 0.f;
#pragma unroll
  for (int d4 = 0; d4 < 16; d4++){
    float4 kv = kr4[d4], qv = qs4[d4];
    s += qv.x*kv.x + qv.y*kv.y + qv.z*kv.z + qv.w*kv.w;
  }
  float mx = blockMax256(s, s4);
  float e = __expf(s - mx);
  float S = blockSum256(e, s4);
  a2[((size_t)h * MLM + im) * MLM + t] = e / S;
}

// ---------------- pinv scale: per-head slots ----------------
__global__ __launch_bounds__(256) void pinv_scale_kernel(
    const float* __restrict__ a2, float* __restrict__ scal){
  const int h = blockIdx.x, j = threadIdx.x;
  const float* A = a2 + (size_t)h * MLM * MLM;
  float rs = 0.f, cs = 0.f;
  for (int t = 0; t < MLM; t++){
    rs += fabsf(A[(size_t)j * MLM + t]);
    cs += fabsf(A[(size_t)t * MLM + j]);
  }
  __shared__ float s4[4];
  float rmax = blockMax256(rs, s4);
  float cmax = blockMax256(cs, s4);
  if (j == 0){ scal[h * 2] = rmax; scal[h * 2 + 1] = cmax; }
}

__global__ __launch_bounds__(256) void pinv_init_kernel(
    const float* __restrict__ a2, const float* __restrict__ scal,
    float* __restrict__ z){
  const int i = blockIdx.x, h = blockIdx.y, j = threadIdx.x;
  float rmax = scal[0], cmax = scal[1];
#pragma unroll
  for (int hh = 1; hh < 8; hh++){
    rmax = fmaxf(rmax, scal[hh * 2]);
    cmax = fmaxf(cmax, scal[hh * 2 + 1]);
  }
  float inv = 1.f / (rmax * cmax);
  z[((size_t)h * MLM + i) * MLM + j] = a2[((size_t)h * MLM + j) * MLM + i] * inv;
}

// ---------------- batched 256^3: split-bf16 MFMA ----------------
__global__ __launch_bounds__(256) void bmm256_mfma_kernel(
    const float* __restrict__ Ab, const float* __restrict__ Bb,
    float* __restrict__ Cb, float c0, float sgn, float c1){
  __shared__ unsigned short Ash[64 * 40], Asl[64 * 40];
  __shared__ unsigned short Bsh[64 * 40], Bsl[64 * 40];
  const int h = blockIdx.z;
  const float* A = Ab + (size_t)h * 65536;
  const float* B = Bb + (size_t)h * 65536;
  float* C = Cb + (size_t)h * 65536;
  const int bm = blockIdx.x * 64, bn = blockIdx.y * 64;
  const int t = threadIdx.x, lane = t & 63, w = t >> 6;
  const int wr = w >> 1, wc = w & 1, m16 = lane & 15, quad = lane >> 4;
  f32x4 z4 = {0.f, 0.f, 0.f, 0.f};
  f32x4 acc[2][2] = {{z4, z4}, {z4, z4}};
  for (int kc = 0; kc < 256; kc += 32){
    {
      int row = t >> 2, c8 = (t & 3) * 8;
      const float* src = A + (size_t)(bm + row) * 256 + kc + c8;
      float xs[8];
      *(float4*)(xs)     = *(const float4*)src;
      *(float4*)(xs + 4) = *(const float4*)(src + 4);
#pragma unroll
      for (int j = 0; j < 8; j++){
        unsigned short hi = f2bf(xs[j]);
        Ash[row * 40 + c8 + j] = hi;
        Asl[row * 40 + c8 + j] = f2bf(xs[j] - bfu(hi));
      }
      int k = t >> 3, n8 = (t & 7) * 8;
      const float* bsrc = B + (size_t)(kc + k) * 256 + bn + n8;
      float ys[8];
      *(float4*)(ys)     = *(const float4*)bsrc;
      *(float4*)(ys + 4) = *(const float4*)(bsrc + 4);
#pragma unroll
      for (int j = 0; j < 8; j++){
        float xv = sgn * ys[j];
        if (kc + k == bn + n8 + j) xv += c0;
        unsigned short hi = f2bf(xv);
        Bsh[(n8 + j) * 40 + k] = hi;
        Bsl[(n8 + j) * 40 + k] = f2bf(xv - bfu(hi));
      }
    }
    __syncthreads();
    bf16x8 ah[2], al[2], bh[2], bl[2];
#pragma unroll
    for (int mi = 0; mi < 2; mi++){
      ah[mi] = *(const bf16x8*)(Ash + (wr * 32 + mi * 16 + m16) * 40 + quad * 8);
      al[mi] = *(const bf16x8*)(Asl + (wr * 32 + mi * 16 + m16) * 40 + quad * 8);
      bh[mi] = *(const bf16x8*)(Bsh + (wc * 32 + mi * 16 + m16) * 40 + quad * 8);
      bl[mi] = *(const bf16x8*)(Bsl + (wc * 32 + mi * 16 + m16) * 40 + quad * 8);
    }
#pragma unroll
    for (int mi = 0; mi < 2; mi++)
#pragma unroll
      for (int ni = 0; ni < 2; ni++){
        acc[mi][ni] = __builtin_amdgcn_mfma_f32_16x16x32_bf16(ah[mi], bh[ni], acc[mi][ni], 0, 0, 0);
        acc[mi][ni] = __builtin_amdgcn_mfma_f32_16x16x32_bf16(ah[mi], bl[ni], acc[mi][ni], 0, 0, 0);
        acc[mi][ni] = __builtin_amdgcn_mfma_f32_16x16x32_bf16(al[mi], bh[ni], acc[mi][ni], 0, 0, 0);
      }
    __syncthreads();
  }
#pragma unroll
  for (int mi = 0; mi < 2; mi++)
#pragma unroll
    for (int ni = 0; ni < 2; ni++)
#pragma unroll
      for (int r = 0; r < 4; r++){
        int row = bm + wr * 32 + mi * 16 + quad * 4 + r;
        int col = bn + wc * 32 + ni * 16 + m16;
        C[(size_t)row * 256 + col] = c1 * acc[mi][ni][r];
      }
}

// ---------------- a3v split-K flash, bf16 MFMA ----------------
__global__ __launch_bounds__(256) void a3v_part_kernel(
    const unsigned short* __restrict__ qlh, const unsigned short* __restrict__ k16,
    const unsigned short* __restrict__ v16, float* __restrict__ pacc,
    float* __restrict__ pml){
  __shared__ __align__(16) unsigned short qs16[64 * 72];
  __shared__ __align__(16) unsigned short kb16[64 * 72];   // K, then P
  __shared__ __align__(16) unsigned short vt16[64 * 72];   // V^T [d][n]
  const int lt = blockIdx.x, h = blockIdx.y, ch = blockIdx.z;
  const int t = threadIdx.x;
  const int lane = t & 63, w = t >> 6;
  const int m16 = lane & 15, quad = lane >> 4;

  const unsigned short* qg = qlh + ((size_t)h * MLM + lt * 64) * HD_;
  for (int idx = t; idx < 512; idx += 256){
    int row = idx >> 3, off = (idx & 7) * 8;
    *(uint4*)(qs16 + row * 72 + off) = *(const uint4*)(qg + (size_t)row * HD_ + off);
  }
  f32x4 z4 = {0.f, 0.f, 0.f, 0.f};
  f32x4 acc_o[4] = {z4, z4, z4, z4};
  float mreg[4], lreg[4];
#pragma unroll
  for (int r = 0; r < 4; r++){ mreg[r] = -3.0e38f; lreg[r] = 0.f; }
  const unsigned short* kg = k16 + ((size_t)h * NP_ + ch * CHTOK) * HD_;
  const unsigned short* vg = v16 + ((size_t)h * NP_ + ch * CHTOK) * HD_;

  for (int sc = 0; sc < 8; sc++){
    __syncthreads();
    for (int idx = t; idx < 512; idx += 256){
      int row = idx >> 3, off = (idx & 7) * 8;
      *(uint4*)(kb16 + row * 72 + off) =
          *(const uint4*)(kg + (size_t)(sc * 64 + row) * HD_ + off);
      uint4 pv = *(const uint4*)(vg + (size_t)(sc * 64 + row) * HD_ + off);
      unsigned int uu[4] = {pv.x, pv.y, pv.z, pv.w};
#pragma unroll
      for (int j = 0; j < 4; j++){
        vt16[(off + 2 * j)     * 72 + row] = (unsigned short)(uu[j] & 0xffffu);
        vt16[(off + 2 * j + 1) * 72 + row] = (unsigned short)(uu[j] >> 16);
      }
    }
    __syncthreads();
    f32x4 acc_s[4] = {z4, z4, z4, z4};
#pragma unroll
    for (int kc = 0; kc < 64; kc += 32){
      bf16x8 a = *(const bf16x8*)(qs16 + (w * 16 + m16) * 72 + kc + quad * 8);
#pragma unroll
      for (int ni = 0; ni < 4; ni++){
        bf16x8 b = *(const bf16x8*)(kb16 + (ni * 16 + m16) * 72 + kc + quad * 8);
        acc_s[ni] = __builtin_amdgcn_mfma_f32_16x16x32_bf16(a, b, acc_s[ni], 0, 0, 0);
      }
    }
    __syncthreads();
#pragma unroll
    for (int r = 0; r < 4; r++){
      float cm = fmaxf(fmaxf(acc_s[0][r], acc_s[1][r]), fmaxf(acc_s[2][r], acc_s[3][r]));
#pragma unroll
      for (int o = 1; o < 16; o <<= 1) cm = fmaxf(cm, __shfl_xor(cm, o));
      float mn = fmaxf(mreg[r], cm);
      float scl = __expf(mreg[r] - mn);
      float p0 = __expf(acc_s[0][r] - mn), p1 = __expf(acc_s[1][r] - mn);
      float p2 = __expf(acc_s[2][r] - mn), p3 = __expf(acc_s[3][r] - mn);
      float ls = (p0 + p1) + (p2 + p3);
#pragma unroll
      for (int o = 1; o < 16; o <<= 1) ls += __shfl_xor(ls, o);
      lreg[r] = lreg[r] * scl + ls;
      mreg[r] = mn;
      acc_o[0][r] *= scl; acc_o[1][r] *= scl;
      acc_o[2][r] *= scl; acc_o[3][r] *= scl;
      int prow = (w * 16 + quad * 4 + r) * 72 + m16;
      kb16[prow + 0]  = f2bf(p0);
      kb16[prow + 16] = f2bf(p1);
      kb16[prow + 32] = f2bf(p2);
      kb16[prow + 48] = f2bf(p3);
    }
    __syncthreads();
#pragma unroll
    for (int kc = 0; kc < 64; kc += 32){
      bf16x8 a = *(const bf16x8*)(kb16 + (w * 16 + m16) * 72 + kc + quad * 8);
#pragma unroll
      for (int ni = 0; ni < 4; ni++){
        bf16x8 b = *(const bf16x8*)(vt16 + (ni * 16 + m16) * 72 + kc + quad * 8);
        acc_o[ni] = __builtin_amdgcn_mfma_f32_16x16x32_bf16(a, b, acc_o[ni], 0, 0, 0);
      }
    }
  }
#pragma unroll
  for (int r = 0; r < 4; r++){
    int im = lt * 64 + w * 16 + quad * 4 + r;
    size_t base = ((size_t)h * NCH + ch) * MLM + im;
#pragma unroll
    for (int ni = 0; ni < 4; ni++)
      pacc[base * HD_ + ni * 16 + m16] = acc_o[ni][r];
    if (m16 == 0){
      pml[base * 2]     = mreg[r];
      pml[base * 2 + 1] = lreg[r];
    }
  }
}

__global__ __launch_bounds__(64) void a3v_combine_kernel(
    const float* __restrict__ pacc, const float* __restrict__ pml,
    float* __restrict__ t1){
  const int im = blockIdx.x, h = blockIdx.y, lane = threadIdx.x;
  float M = -3.0e38f;
  for (int c = 0; c < NCH; c++)
    M = fmaxf(M, pml[(((size_t)h * NCH + c) * MLM + im) * 2]);
  float accv = 0.f, L = 0.f;
  for (int c = 0; c < NCH; c++){
    size_t base = ((size_t)h * NCH + c) * MLM + im;
    float mc = pml[base * 2], lc = pml[base * 2 + 1];
    float w = __expf(mc - M);
    accv += w * pacc[base * HD_ + lane];
    L += w * lc;
  }
  t1[((size_t)h * MLM + im) * HD_ + lane] = accv / L;
}

// ---------------- t2^T = (z @ t1)^T, bf16 [h][d][im] ----------------
__global__ __launch_bounds__(256) void zt1_kernel(
    const float* __restrict__ z, const float* __restrict__ t1,
    unsigned short* __restrict__ t2t){
  const int h = blockIdx.y;
  const int t = threadIdx.x;
  const int d = t & 63, ri = t >> 6;
  const int im = blockIdx.x * 4 + ri;
  const float* zr = z + ((size_t)h * MLM + im) * MLM;
  const float* t1h = t1 + (size_t)h * MLM * HD_;
  float acc = 0.f;
#pragma unroll 8
  for (int kk = 0; kk < MLM; kk++) acc += zr[kk] * t1h[(size_t)kk * HD_ + d];
  t2t[((size_t)h * HD_ + d) * MLM + im] = f2bf(acc);
}

// ---------------- out tile MFMA: 64 tokens x 1 head per block ----------------
__global__ __launch_bounds__(256) void out_tile_kernel(
    const unsigned short* __restrict__ q16, const unsigned short* __restrict__ klh,
    const unsigned short* __restrict__ t2t, const unsigned short* __restrict__ v16,
    const float* __restrict__ resw, unsigned short* __restrict__ outh){
  __shared__ __align__(16) unsigned short smem[64 * 72 * 2 + 64 * 264];
  unsigned short* qs16 = smem;                 // 64 x 72
  unsigned short* kb16 = smem + 64 * 72;       // 64 x 72 (kl chunks, t2t chunks)
  unsigned short* Ps   = smem + 64 * 72 * 2;   // 64 x 264 (P bf16; later O f32 + v tile)
  const int tile = blockIdx.x, h = blockIdx.y;
  const int n0 = PADR + tile * 64;
  const int t = threadIdx.x;
  const int lane = t & 63, w = t >> 6;
  const int m16 = lane & 15, quad = lane >> 4;

  {
    const unsigned short* qh = q16 + (size_t)h * NP_ * HD_;
    for (int idx = t; idx < 512; idx += 256){
      int row = idx >> 3, off = (idx & 7) * 8;
      int n = n0 + row;
      uint4 val = {0u, 0u, 0u, 0u};
      if (n < NP_) val = *(const uint4*)(qh + (size_t)n * HD_ + off);
      *(uint4*)(qs16 + row * 72 + off) = val;
    }
  }
  f32x4 z4 = {0.f, 0.f, 0.f, 0.f};
  f32x4 acc_s[16];
#pragma unroll
  for (int i = 0; i < 16; i++) acc_s[i] = z4;
  const unsigned short* klg = klh + (size_t)h * MLM * HD_;
  for (int m = 0; m < 4; m++){
    __syncthreads();
    for (int idx = t; idx < 512; idx += 256){
      int row = idx >> 3, off = (idx & 7) * 8;
      *(uint4*)(kb16 + row * 72 + off) =
          *(const uint4*)(klg + (size_t)(m * 64 + row) * HD_ + off);
    }
    __syncthreads();
#pragma unroll
    for (int kc = 0; kc < 64; kc += 32){
      bf16x8 a = *(const bf16x8*)(qs16 + (w * 16 + m16) * 72 + kc + quad * 8);
#pragma unroll
      for (int ni = 0; ni < 4; ni++){
        bf16x8 b = *(const bf16x8*)(kb16 + (ni * 16 + m16) * 72 + kc + quad * 8);
        acc_s[m * 4 + ni] = __builtin_amdgcn_mfma_f32_16x16x32_bf16(a, b, acc_s[m * 4 + ni], 0, 0, 0);
      }
    }
  }
  __syncthreads();
#pragma unroll
  for (int r = 0; r < 4; r++){
    float mx = acc_s[0][r];
#pragma unroll
    for (int mc = 1; mc < 16; mc++) mx = fmaxf(mx, acc_s[mc][r]);
#pragma unroll
    for (int o = 1; o < 16; o <<= 1) mx = fmaxf(mx, __shfl_xor(mx, o));
    float p[16]; float sum = 0.f;
#pragma unroll
    for (int mc = 0; mc < 16; mc++){ p[mc] = __expf(acc_s[mc][r] - mx); sum += p[mc]; }
#pragma unroll
    for (int o = 1; o < 16; o <<= 1) sum += __shfl_xor(sum, o);
    float inv = 1.f / sum;
    int prow = (w * 16 + quad * 4 + r) * 264;
#pragma unroll
    for (int mc = 0; mc < 16; mc++)
      Ps[prow + (mc >> 2) * 64 + (mc & 3) * 16 + m16] = f2bf(p[mc] * inv);
  }
  f32x4 acc_o[4] = {z4, z4, z4, z4};
  const unsigned short* t2g = t2t + (size_t)h * HD_ * MLM;
  for (int ch = 0; ch < 4; ch++){
    __syncthreads();
    {
      int row = t >> 2, c8 = (t & 3) * 16;
      const unsigned short* src = t2g + (size_t)row * MLM + ch * 64 + c8;
      *(uint4*)(kb16 + row * 72 + c8)     = *(const uint4*)src;
      *(uint4*)(kb16 + row * 72 + c8 + 8) = *(const uint4*)(src + 8);
    }
    __syncthreads();
#pragma unroll
    for (int kc = 0; kc < 64; kc += 32){
      bf16x8 a = *(const bf16x8*)(Ps + (w * 16 + m16) * 264 + ch * 64 + kc + quad * 8);
#pragma unroll
      for (int ni = 0; ni < 4; ni++){
        bf16x8 b = *(const bf16x8*)(kb16 + (ni * 16 + m16) * 72 + kc + quad * 8);
        acc_o[ni] = __builtin_amdgcn_mfma_f32_16x16x32_bf16(a, b, acc_o[ni], 0, 0, 0);
      }
    }
  }
  __syncthreads();
  float* Obuf = (float*)Ps;                          // 64 x 66 f32
  unsigned short* vtile = (unsigned short*)(Obuf + 64 * 66);  // 96 x 72 bf16
#pragma unroll
  for (int r = 0; r < 4; r++){
    int row = w * 16 + quad * 4 + r;
#pragma unroll
    for (int ni = 0; ni < 4; ni++)
      Obuf[row * 66 + ni * 16 + m16] = acc_o[ni][r];
  }
  {
    const unsigned short* vh = v16 + (size_t)h * NP_ * HD_;
    for (int idx = t; idx < 768; idx += 256){
      int row = idx >> 3, off = (idx & 7) * 8;
      int nn = n0 - 16 + row;
      uint4 val = {0u, 0u, 0u, 0u};
      if (nn < NP_) val = *(const uint4*)(vh + (size_t)nn * HD_ + off);
      *(uint4*)(vtile + row * 72 + off) = val;
    }
  }
  __syncthreads();
  float wreg[33];
  {
    const float* wr = resw + h * 33;
#pragma unroll
    for (int kk = 0; kk < 33; kk++) wreg[kk] = wr[kk];
  }
  const int ty = t >> 4, tx = t & 15;
#pragma unroll
  for (int i = 0; i < 4; i++){
    int lrow = ty * 4 + i;
    float c0v = 0.f, c1v = 0.f, c2v = 0.f, c3v = 0.f;
    for (int kk = 0; kk < 33; kk++){
      uint2 uv = *(const uint2*)(vtile + (lrow + kk) * 72 + tx * 4);
      float wv = wreg[kk];
      c0v += __uint_as_float(uv.x << 16) * wv;
      c1v += __uint_as_float(uv.x & 0xffff0000u) * wv;
      c2v += __uint_as_float(uv.y << 16) * wv;
      c3v += __uint_as_float(uv.y & 0xffff0000u) * wv;
    }
    int trow = tile * 64 + lrow;
    if (trow < NTOK){
      const float* orow = Obuf + lrow * 66 + tx * 4;
      unsigned long long pk =
          (unsigned long long)f2bf(orow[0] + c0v)
        | ((unsigned long long)f2bf(orow[1] + c1v) << 16)
        | ((unsigned long long)f2bf(orow[2] + c2v) << 32)
        | ((unsigned long long)f2bf(orow[3] + c3v) << 48);
      *(unsigned long long*)(outh + (size_t)trow * D_ + h * HD_ + tx * 4) = pk;
    }
  }
}

// ---------------- proj MFMA: h += outh @ out_wt^T + bias ----------------
// grid (163, 4)
__global__ __launch_bounds__(256) void proj_mfma_kernel(
    const unsigned short* __restrict__ A, const unsigned short* __restrict__ Bt,
    const float* __restrict__ bias, float* __restrict__ h){
  __shared__ unsigned short As[128 * 72], Bs[128 * 72];
  f32x4 z4 = {0.f, 0.f, 0.f, 0.f};
  f32x4 acc[4][4];
#pragma unroll
  for (int i = 0; i < 4; i++)
#pragma unroll
    for (int j = 0; j < 4; j++) acc[i][j] = z4;
  const int bm = blockIdx.x * 128, bn = blockIdx.y * 128;
  mfma_tile128(A, NTOK, bm, Bt, bn, D_, acc, As, Bs);
  const int lane = threadIdx.x & 63, wave = threadIdx.x >> 6;
  const int wr = wave >> 1, wc = wave & 1;
  const int m16 = lane & 15, quad = lane >> 4;
#pragma unroll
  for (int mi = 0; mi < 4; mi++)
#pragma unroll
    for (int ni = 0; ni < 4; ni++){
      int col = bn + wc * 64 + ni * 16 + m16;
      float bv = bias[col];
#pragma unroll
      for (int r = 0; r < 4; r++){
        int row = bm + wr * 64 + mi * 16 + quad * 4 + r;
        if (row < NTOK) h[(size_t)row * D_ + col] += acc[mi][ni][r] + bv;
      }
    }
}

// ---------------- PPEG ----------------
__global__ __launch_bounds__(512) void ppeg_combine_kernel(
    const float* __restrict__ w7, const float* __restrict__ b7,
    const float* __restrict__ w5, const float* __restrict__ b5,
    const float* __restrict__ w3, const float* __restrict__ b3,
    float* __restrict__ wcomb, float* __restrict__ bcomb){
  const int c = threadIdx.x;
#pragma unroll
  for (int i = 0; i < 7; i++){
#pragma unroll
    for (int j = 0; j < 7; j++){
      int di = i - 3, dj = j - 3;
      float wv = w7[(size_t)c * 49 + i * 7 + j];
      if (di >= -2 && di <= 2 && dj >= -2 && dj <= 2)
        wv += w5[(size_t)c * 25 + (di + 2) * 5 + (dj + 2)];
      if (di >= -1 && di <= 1 && dj >= -1 && dj <= 1)
        wv += w3[(size_t)c * 9 + (di + 1) * 3 + (dj + 1)];
      if (di == 0 && dj == 0) wv += 1.f;
      wcomb[(size_t)(i * 7 + j) * 512 + c] = wv;
    }
  }
  bcomb[c] = b7[c] + b5[c] + b3[c];
}

// writes conv result DIRECTLY into h2 rows 1.. (ping-pong; no copy kernel)
__global__ __launch_bounds__(512) void ppeg_conv_kernel(
    const float* __restrict__ h, const float* __restrict__ wcomb,
    const float* __restrict__ bcomb, float* __restrict__ h2){
  const int c = threadIdx.x;
  const int y = blockIdx.y;
  const int x0 = blockIdx.x * 8;
  float wc[49];
#pragma unroll
  for (int kk = 0; kk < 49; kk++) wc[kk] = wcomb[(size_t)kk * 512 + c];
  float acc[8];
  const float bv = bcomb[c];
#pragma unroll
  for (int p = 0; p < 8; p++) acc[p] = bv;
#pragma unroll
  for (int i = 0; i < 7; i++){
    const int yy = y + i - 3;
    if (yy < 0 || yy >= HHW) continue;
    const float* hrow = h + (size_t)(1 + yy * HHW) * D_ + c;
    float line[14];
#pragma unroll
    for (int j = 0; j < 14; j++){
      const int xx = x0 + j - 3;
      line[j] = (xx >= 0 && xx < HHW) ? hrow[(size_t)xx * D_] : 0.f;
    }
#pragma unroll
    for (int p = 0; p < 8; p++)
#pragma unroll
      for (int j = 0; j < 7; j++)
        acc[p] += line[p + j] * wc[i * 7 + j];
  }
#pragma unroll
  for (int p = 0; p < 8; p++)
    h2[(size_t)(1 + y * HHW + x0 + p) * D_ + c] = acc[p];
}

// ---------------- final ----------------
__global__ __launch_bounds__(512) void final_kernel(
    const float* __restrict__ h, const float* __restrict__ w,
    const float* __restrict__ b, const float* __restrict__ fc3w,
    const float* __restrict__ fc3b, float* __restrict__ out){
  __shared__ float vec[512];
  __shared__ float s8[8];
  __shared__ float lg[4];
  const int t = threadIdx.x;
  float x = h[t];
  float v = waveSumF(x);
  if ((t & 63) == 0) s8[t >> 6] = v;
  __syncthreads();
  float sum = 0.f;
#pragma unroll
  for (int i = 0; i < 8; i++) sum += s8[i];
  float mu = sum * (1.f / 512.f);
  __syncthreads();
  float d = x - mu;
  v = waveSumF(d * d);
  if ((t & 63) == 0) s8[t >> 6] = v;
  __syncthreads();
  float var = 0.f;
#pragma unroll
  for (int i = 0; i < 8; i++) var += s8[i];
  var *= (1.f / 512.f);
  float rs = rsqrtf(var + 1e-5f);
  vec[t] = d * rs * w[t] + b[t];
  __syncthreads();
  if (t < 4){
    float acc = fc3b[t];
    for (int kk = 0; kk < 512; kk++) acc += vec[kk] * fc3w[kk * 4 + t];
    lg[t] = acc;
  }
  __syncthreads();
  if (t == 0){
    float m = fmaxf(fmaxf(lg[0], lg[1]), fmaxf(lg[2], lg[3]));
    float e[4], se = 0.f;
#pragma unroll
    for (int i = 0; i < 4; i++){ e[i] = __expf(lg[i] - m); se += e[i]; }
    int am = 0; float bm = lg[0];
#pragma unroll
    for (int i = 1; i < 4; i++) if (lg[i] > bm){ bm = lg[i]; am = i; }
#pragma unroll
    for (int i = 0; i < 4; i++){ out[i] = lg[i]; out[4 + i] = e[i] / se; }
    out[8] = (float)am;
  }
}

// ---------------------------------------------------------------------------
extern "C" void kernel_launch(void* const* d_in, const int* in_sizes, int n_in,
                              void* d_out, int out_size, void* d_ws, size_t ws_size,
                              hipStream_t stream) {
  const float* x       = (const float*)d_in[0];
  const float* fc1_w   = (const float*)d_in[1];
  const float* fc1_b   = (const float*)d_in[2];
  const float* cls_tok = (const float*)d_in[3];
  const float* l1_nw   = (const float*)d_in[4];
  const float* l1_nb   = (const float*)d_in[5];
  const float* l1_qkvw = (const float*)d_in[6];
  const float* l1_outw = (const float*)d_in[7];
  const float* l1_outb = (const float*)d_in[8];
  const float* l1_resw = (const float*)d_in[9];
  const float* ppeg_w7 = (const float*)d_in[10];
  const float* ppeg_b7 = (const float*)d_in[11];
  const float* ppeg_w5 = (const float*)d_in[12];
  const float* ppeg_b5 = (const float*)d_in[13];
  const float* ppeg_w3 = (const float*)d_in[14];
  const float* ppeg_b3 = (const float*)d_in[15];
  const float* l2_nw   = (const float*)d_in[16];
  const float* l2_nb   = (const float*)d_in[17];
  const float* l2_qkvw = (const float*)d_in[18];
  const float* l2_outw = (const float*)d_in[19];
  const float* l2_outb = (const float*)d_in[20];
  const float* l2_resw = (const float*)d_in[21];
  const float* norm_w  = (const float*)d_in[22];
  const float* norm_b  = (const float*)d_in[23];
  const float* fc3_w   = (const float*)d_in[24];
  const float* fc3_b   = (const float*)d_in[25];

  // workspace layout (float units)
  float* W = (float*)d_ws;
  size_t o = 0;
  float* hbuf = W + o; o += (size_t)NTOK * D_;
  float* xp   = W + o; o += (size_t)NP_ * D_;   // xph / pacc+pml / outh
  float* qb   = W + o; o += (size_t)NH_ * NP_ * HD_;   // bf16 q; also Ah pre-layer
  float* kb   = W + o; o += (size_t)NH_ * NP_ * HD_;   // bf16 k
  float* vb   = W + o; o += (size_t)NH_ * NP_ * HD_;   // bf16 v
  float* qlb  = W + o; o += (size_t)NH_ * MLM * HD_;
  float* klb  = W + o; o += (size_t)NH_ * MLM * HD_;
  float* a2b  = W + o; o += (size_t)NH_ * MLM * MLM;
  float* z0   = W + o; o += (size_t)NH_ * MLM * MLM;
  float* z1   = W + o; o += (size_t)NH_ * MLM * MLM;
  float* ta   = W + o; o += (size_t)NH_ * MLM * MLM;
  float* tb   = W + o; o += (size_t)NH_ * MLM * MLM;
  float* tc   = W + o; o += (size_t)NH_ * MLM * MLM;
  float* t1b  = W + o; o += (size_t)NH_ * MLM * HD_;
  float* t2r  = W + o; o += (size_t)NH_ * MLM * HD_;   // t2t bf16 lives here
  float* scalf = W + o; o += 16;
  float* wcomb = W + o; o += 49 * 512;
  float* bcomb = W + o; o += 512;
  unsigned short* fc1_wt  = (unsigned short*)(W + o); o += (size_t)D_ * E_ / 2;
  unsigned short* qkv_wt1 = (unsigned short*)(W + o); o += (size_t)1536 * D_ / 2;
  unsigned short* qkv_wt2 = (unsigned short*)(W + o); o += (size_t)1536 * D_ / 2;
  unsigned short* out_wt1 = (unsigned short*)(W + o); o += (size_t)D_ * D_ / 2;
  unsigned short* out_wt2 = (unsigned short*)(W + o); o += (size_t)D_ * D_ / 2;
  unsigned short* qlh = (unsigned short*)(W + o); o += (size_t)NH_ * MLM * HD_ / 2;
  unsigned short* klh = (unsigned short*)(W + o); o += (size_t)NH_ * MLM * HD_ / 2;
  float* hbuf2 = W + o; o += (size_t)NTOK * D_;       // ppeg ping-pong target

  unsigned short* xph = (unsigned short*)xp;
  float* pacc = xp;
  float* pml  = xp + (size_t)NH_ * NCH * MLM * HD_;
  unsigned short* outh = (unsigned short*)xp;
  unsigned short* Ah  = (unsigned short*)qb;
  unsigned short* q16 = (unsigned short*)qb;
  unsigned short* k16 = (unsigned short*)kb;
  unsigned short* v16 = (unsigned short*)vb;
  unsigned short* t2t = (unsigned short*)t2r;

  // ---- weight prep (once per launch) ----
  wtrans_kernel<<<dim3(E_ / 32, D_ / 32), dim3(32, 8), 0, stream>>>(fc1_w, fc1_wt, E_, D_);
  wtrans_kernel<<<dim3(D_ / 32, 1536 / 32), dim3(32, 8), 0, stream>>>(l1_qkvw, qkv_wt1, D_, 1536);
  wtrans_kernel<<<dim3(D_ / 32, 1536 / 32), dim3(32, 8), 0, stream>>>(l2_qkvw, qkv_wt2, D_, 1536);
  wtrans_kernel<<<dim3(D_ / 32, D_ / 32), dim3(32, 8), 0, stream>>>(l1_outw, out_wt1, D_, D_);
  wtrans_kernel<<<dim3(D_ / 32, D_ / 32), dim3(32, 8), 0, stream>>>(l2_outw, out_wt2, D_, D_);
  ppeg_combine_kernel<<<1, 512, 0, stream>>>(ppeg_w7, ppeg_b7, ppeg_w5, ppeg_b5,
                                             ppeg_w3, ppeg_b3, wcomb, bcomb);

  // ---- fc1 (maxpool -> bf16 -> MFMA 128-tile) ----
  pool_bf16_kernel<<<20480, 256, 0, stream>>>(x, Ah);
  fc1_mfma_kernel<<<dim3(160, 4), 256, 0, stream>>>(Ah, fc1_wt, fc1_b, hbuf);
  cls_kernel<<<2, 256, 0, stream>>>(cls_tok, hbuf);

  auto run_layer = [&](float* hcur, const float* nw, const float* nb,
                       const unsigned short* qkvwt, const unsigned short* outwt,
                       const float* outb, const float* resw){
    ln_pad_kernel<<<NP_, 256, 0, stream>>>(hcur, nw, nb, xph);
    qkv_mfma_kernel<<<dim3(164, 12), 256, 0, stream>>>(xph, qkvwt, q16, k16, v16);
    landmark_kernel<<<dim3(256, 8), 64, 0, stream>>>(q16, k16, qlb, klb, qlh, klh);
    a2_kernel<<<dim3(256, 8), 256, 0, stream>>>(qlb, klb, a2b);
    pinv_scale_kernel<<<8, 256, 0, stream>>>(a2b, scalf);
    pinv_init_kernel<<<dim3(256, 8), 256, 0, stream>>>(a2b, scalf, z0);
    float* zc = z0; float* za = z1;
    for (int it = 0; it < 6; it++){
      bmm256_mfma_kernel<<<dim3(4, 4, 8), 256, 0, stream>>>(a2b, zc, ta, 0.f, 1.f, 1.f);
      bmm256_mfma_kernel<<<dim3(4, 4, 8), 256, 0, stream>>>(ta, ta, tb, 7.f, -1.f, 1.f);
      bmm256_mfma_kernel<<<dim3(4, 4, 8), 256, 0, stream>>>(ta, tb, tc, 15.f, -1.f, 1.f);
      bmm256_mfma_kernel<<<dim3(4, 4, 8), 256, 0, stream>>>(zc, tc, za, 13.f, -1.f, 0.25f);
      float* tswap = zc; zc = za; za = tswap;
    }
    a3v_part_kernel<<<dim3(4, 8, NCH), 256, 0, stream>>>(qlh, k16, v16, pacc, pml);
    a3v_combine_kernel<<<dim3(256, 8), 64, 0, stream>>>(pacc, pml, t1b);
    zt1_kernel<<<dim3(64, 8), 256, 0, stream>>>(zc, t1b, t2t);
    out_tile_kernel<<<dim3(325, 8), 256, 0, stream>>>(q16, klh, t2t, v16, resw, outh);
    proj_mfma_kernel<<<dim3(163, 4), 256, 0, stream>>>(outh, outwt, outb, hcur);
  };

  run_layer(hbuf, l1_nw, l1_nb, qkv_wt1, out_wt1, l1_outb, l1_resw);
  // PPEG: conv writes rows 1.. of hbuf2 directly; cls row copied
  ppeg_conv_kernel<<<dim3(HHW / 8, HHW), 512, 0, stream>>>(hbuf, wcomb, bcomb, hbuf2);
  row0_copy_kernel<<<2, 256, 0, stream>>>(hbuf, hbuf2);
  run_layer(hbuf2, l2_nw, l2_nb, qkv_wt2, out_wt2, l2_outb, l2_resw);
  final_kernel<<<1, 512, 0, stream>>>(hbuf2, norm_w, norm_b, fc3_w, fc3_b, (float*)d_out);
}